// Round 1
// baseline (1138.571 us; speedup 1.0000x reference)
//
#include <hip/hip_runtime.h>
#include <hip/hip_bf16.h>
#include <math.h>

#define NODES 50000
#define EDGES 1600000
#define HD    128
#define NC    40
#define EPSV  1e-5f

// ---------------- graph build ----------------

__global__ void k_deg(const int* __restrict__ dst, int* __restrict__ counts, int e_) {
  int e = blockIdx.x * 256 + threadIdx.x;
  if (e < e_) atomicAdd(&counts[dst[e]], 1);
}

__global__ void k_dis(const int* __restrict__ counts, float* __restrict__ dis, int n) {
  int i = blockIdx.x * 256 + threadIdx.x;
  if (i < n) dis[i] = rsqrtf((float)(counts[i] + 1));  // deg = indeg + self-loop >= 1
}

// single-block scan: row_ptr (exclusive in row_ptr[i], total in row_ptr[n]), cursor = exclusive
__global__ void k_scan(const int* __restrict__ counts, int* __restrict__ row_ptr,
                       int* __restrict__ cursor, int n) {
  __shared__ int wsum[16];
  int tid = threadIdx.x, lane = tid & 63, wid = tid >> 6;
  int running = 0;
  for (int base = 0; base < n; base += 1024) {
    int i = base + tid;
    int v = (i < n) ? counts[i] : 0;
    int x = v;
#pragma unroll
    for (int off = 1; off < 64; off <<= 1) {
      int y = __shfl_up(x, off, 64);
      if (lane >= off) x += y;
    }
    if (lane == 63) wsum[wid] = x;
    __syncthreads();
    if (wid == 0) {
      int s = (lane < 16) ? wsum[lane] : 0;
#pragma unroll
      for (int off = 1; off < 16; off <<= 1) {
        int y = __shfl_up(s, off, 64);
        if (lane >= off) s += y;
      }
      if (lane < 16) wsum[lane] = s;
    }
    __syncthreads();
    int wofs = (wid > 0) ? wsum[wid - 1] : 0;
    int incl = running + wofs + x;
    if (i < n) { row_ptr[i + 1] = incl; cursor[i] = incl - v; }
    running += wsum[15];
    __syncthreads();
  }
  if (tid == 0) row_ptr[0] = 0;
}

__global__ void k_fill(const int* __restrict__ src, const int* __restrict__ dst,
                       const float* __restrict__ dis, int* __restrict__ cursor,
                       int* __restrict__ csr_src, float* __restrict__ csr_w, int e_) {
  int e = blockIdx.x * 256 + threadIdx.x;
  if (e >= e_) return;
  int s = src[e], d = dst[e];
  int idx = atomicAdd(&cursor[d], 1);
  csr_src[idx] = s;
  csr_w[idx] = dis[s] * dis[d];
}

// ---------------- fp32 GEMM: C[n,128] = A[n,128] @ B[128,128] ----------------
// 64x64 tile per 256-thread block, 4x4 register blocking, full K staged in LDS.
__global__ __launch_bounds__(256)
void k_gemm(const float* __restrict__ A, const float* __restrict__ B,
            float* __restrict__ Cmat, int n) {
  __shared__ float As[64 * 132];   // [row][k], pad 128->132 to break bank alias
  __shared__ float Bs[128 * 64];   // [k][col]
  int tid = threadIdx.x;
  int rowBase = blockIdx.x * 64;
  int c0 = blockIdx.y * 64;

#pragma unroll
  for (int i = 0; i < 8; ++i) {
    int f = tid + i * 256;        // float4 index within 64x128 tile
    int row = f >> 5;             // 32 float4 per row
    int kc = (f & 31) << 2;
    float4 v = make_float4(0.f, 0.f, 0.f, 0.f);
    int rg = rowBase + row;
    if (rg < n) v = *(const float4*)&A[(size_t)rg * 128 + kc];
    *(float4*)&As[row * 132 + kc] = v;
  }
#pragma unroll
  for (int i = 0; i < 8; ++i) {
    int f = tid + i * 256;        // float4 index within 128x64 tile
    int k = f >> 4;               // 16 float4 per row of the tile
    int c = (f & 15) << 2;
    *(float4*)&Bs[k * 64 + c] = *(const float4*)&B[(size_t)k * 128 + c0 + c];
  }
  __syncthreads();

  int tc = (tid & 15) << 2;
  int tr = (tid >> 4) << 2;
  float acc[4][4] = {};
#pragma unroll 4
  for (int k = 0; k < 128; ++k) {
    float4 b = *(const float4*)&Bs[k * 64 + tc];
#pragma unroll
    for (int i = 0; i < 4; ++i) {
      float a = As[(tr + i) * 132 + k];
      acc[i][0] = fmaf(a, b.x, acc[i][0]);
      acc[i][1] = fmaf(a, b.y, acc[i][1]);
      acc[i][2] = fmaf(a, b.z, acc[i][2]);
      acc[i][3] = fmaf(a, b.w, acc[i][3]);
    }
  }
#pragma unroll
  for (int i = 0; i < 4; ++i) {
    int rg = rowBase + tr + i;
    if (rg < n) {
      float4 o = make_float4(acc[i][0], acc[i][1], acc[i][2], acc[i][3]);
      *(float4*)&Cmat[(size_t)rg * 128 + c0 + tc] = o;
    }
  }
}

// ---------------- aggregation: h[d] = dis[d]^2*t[d] + sum_e w_e * t[src_e] + b ----------------
// one wave per node, lane owns 2 features (float2), atomic-free via CSR.
__global__ __launch_bounds__(256)
void k_agg(const float* __restrict__ t, const int* __restrict__ row_ptr,
           const int* __restrict__ csr_src, const float* __restrict__ csr_w,
           const float* __restrict__ dis, const float* __restrict__ bias,
           float* __restrict__ h, int n) {
  int lane = threadIdx.x & 63;
  int node = (blockIdx.x * 256 + threadIdx.x) >> 6;
  if (node >= n) return;
  int k0 = lane << 1;
  float d = dis[node];
  float2 sv = *(const float2*)&t[(size_t)node * 128 + k0];
  float acc0 = d * d * sv.x, acc1 = d * d * sv.y;
  int e = row_ptr[node], end = row_ptr[node + 1];
  for (; e < end; ++e) {
    int s = csr_src[e];
    float w = csr_w[e];
    float2 v = *(const float2*)&t[(size_t)s * 128 + k0];
    acc0 = fmaf(w, v.x, acc0);
    acc1 = fmaf(w, v.y, acc1);
  }
  acc0 += bias[k0];
  acc1 += bias[k0 + 1];
  *(float2*)&h[(size_t)node * 128 + k0] = make_float2(acc0, acc1);
}

// ---------------- BN stats: stats[f]=sum, stats[128+f]=sumsq ----------------
__global__ __launch_bounds__(256)
void k_stats(const float* __restrict__ h, float* __restrict__ stats, int n, int rows_per_block) {
  int f = threadIdx.x & 127;
  int half = threadIdx.x >> 7;  // 0..1
  int r0 = blockIdx.x * rows_per_block;
  int r1 = min(n, r0 + rows_per_block);
  float s0 = 0.f, s1 = 0.f;
  for (int r = r0 + half; r < r1; r += 2) {
    float v = h[(size_t)r * 128 + f];
    s0 += v;
    s1 += v * v;
  }
  __shared__ float l0[256], l1[256];
  l0[threadIdx.x] = s0;
  l1[threadIdx.x] = s1;
  __syncthreads();
  if (threadIdx.x < 128) {
    s0 = l0[threadIdx.x] + l0[threadIdx.x + 128];
    s1 = l1[threadIdx.x] + l1[threadIdx.x + 128];
    atomicAdd(&stats[f], s0);
    atomicAdd(&stats[128 + f], s1);
  }
}

// ---------------- BN normalize + ReLU (in place) ----------------
__global__ __launch_bounds__(256)
void k_bnrelu(float* __restrict__ h, const float* __restrict__ stats,
              const float* __restrict__ g, const float* __restrict__ be, int n) {
  int idx4 = blockIdx.x * 256 + threadIdx.x;  // float4 index
  if (idx4 >= n * 32) return;                 // n*128/4
  int f = (idx4 & 31) << 2;
  const float inv_n = 1.0f / (float)n;
  float4 v = *(float4*)&h[(size_t)idx4 * 4];
  float4 o;
#pragma unroll
  for (int j = 0; j < 4; ++j) {
    float m = stats[f + j] * inv_n;
    float var = stats[128 + f + j] * inv_n - m * m;
    float rstd = rsqrtf(var + EPSV);
    float x = ((&v.x)[j] - m) * rstd * g[f + j] + be[f + j];
    (&o.x)[j] = fmaxf(x, 0.f);
  }
  *(float4*)&h[(size_t)idx4 * 4] = o;
}

// ---------------- FC + ReLU + log_softmax: one wave per node ----------------
__global__ __launch_bounds__(256)
void k_fc(const float* __restrict__ h, const float* __restrict__ W,
          const float* __restrict__ b, float* __restrict__ out, int n) {
  int lane = threadIdx.x & 63;
  int node = (blockIdx.x * 256 + threadIdx.x) >> 6;
  if (node >= n) return;
  const float* hr = h + (size_t)node * 128;
  bool act = lane < NC;
  float acc = act ? b[lane] : 0.f;
  for (int k = 0; k < 128; ++k) {
    float a = hr[k];
    float w = act ? W[k * NC + lane] : 0.f;
    acc = fmaf(a, w, acc);
  }
  float logit = act ? fmaxf(acc, 0.f) : 0.f;
  float mv = act ? logit : -1e30f;
#pragma unroll
  for (int off = 32; off; off >>= 1) mv = fmaxf(mv, __shfl_xor(mv, off, 64));
  float ex = act ? __expf(logit - mv) : 0.f;
  float sum = ex;
#pragma unroll
  for (int off = 32; off; off >>= 1) sum += __shfl_xor(sum, off, 64);
  float lse = mv + __logf(sum);
  if (act) {
    out[(size_t)node * NC + lane] = logit - lse;
    out[(size_t)NODES * NC + (size_t)node * NC + lane] = logit;
  }
}

// ---------------- launch ----------------

extern "C" void kernel_launch(void* const* d_in, const int* in_sizes, int n_in,
                              void* d_out, int out_size, void* d_ws, size_t ws_size,
                              hipStream_t stream) {
  (void)in_sizes; (void)n_in; (void)out_size; (void)ws_size;
  const float* x   = (const float*)d_in[0];
  const int*   ei  = (const int*)d_in[1];
  const float* W1  = (const float*)d_in[2];
  const float* b1  = (const float*)d_in[3];
  const float* W2  = (const float*)d_in[4];
  const float* b2  = (const float*)d_in[5];
  const float* W3  = (const float*)d_in[6];
  const float* b3  = (const float*)d_in[7];
  const float* g1  = (const float*)d_in[8];
  const float* be1 = (const float*)d_in[9];
  const float* g2  = (const float*)d_in[10];
  const float* be2 = (const float*)d_in[11];
  const float* g3  = (const float*)d_in[12];
  const float* be3 = (const float*)d_in[13];
  const float* fcW = (const float*)d_in[14];
  const float* fcb = (const float*)d_in[15];
  float* out = (float*)d_out;

  const int n = NODES, e_ = EDGES;
  const int* srcp = ei;        // edge_index[0]
  const int* dstp = ei + e_;   // edge_index[1]

  char* ws = (char*)d_ws;
  size_t off = 0;
  auto alloc = [&](size_t bytes) {
    char* p = ws + off;
    off = (off + bytes + 255) & ~(size_t)255;
    return p;
  };
  float* dis    = (float*)alloc((size_t)n * 4);
  int*   counts = (int*)  alloc((size_t)n * 4);
  int*   row_ptr= (int*)  alloc((size_t)(n + 1) * 4);
  int*   cursor = (int*)  alloc((size_t)n * 4);
  int*   csr_src= (int*)  alloc((size_t)e_ * 4);
  float* csr_w  = (float*)alloc((size_t)e_ * 4);
  float* tbuf   = (float*)alloc((size_t)n * HD * 4);
  float* hbuf   = (float*)alloc((size_t)n * HD * 4);
  float* stats  = (float*)alloc(256 * 4);

  hipMemsetAsync(counts, 0, (size_t)n * 4, stream);
  k_deg<<<(e_ + 255) / 256, 256, 0, stream>>>(dstp, counts, e_);
  k_dis<<<(n + 255) / 256, 256, 0, stream>>>(counts, dis, n);
  k_scan<<<1, 1024, 0, stream>>>(counts, row_ptr, cursor, n);
  k_fill<<<(e_ + 255) / 256, 256, 0, stream>>>(srcp, dstp, dis, cursor, csr_src, csr_w, e_);

  dim3 ggrid((n + 63) / 64, 2);
  const int rows_per_block = (n + 255) / 256;
  const float* in_ptr = x;
  const float* Wl[3]  = {W1, W2, W3};
  const float* bl[3]  = {b1, b2, b3};
  const float* gl[3]  = {g1, g2, g3};
  const float* bel[3] = {be1, be2, be3};
  for (int L = 0; L < 3; ++L) {
    k_gemm<<<ggrid, 256, 0, stream>>>(in_ptr, Wl[L], tbuf, n);
    k_agg<<<(n + 3) / 4, 256, 0, stream>>>(tbuf, row_ptr, csr_src, csr_w, dis, bl[L], hbuf, n);
    hipMemsetAsync(stats, 0, 256 * 4, stream);
    k_stats<<<256, 256, 0, stream>>>(hbuf, stats, n, rows_per_block);
    k_bnrelu<<<(n * 32 + 255) / 256, 256, 0, stream>>>(hbuf, stats, gl[L], bel[L], n);
    in_ptr = hbuf;
  }
  k_fc<<<(n + 3) / 4, 256, 0, stream>>>(hbuf, fcW, fcb, out, n);
}

// Round 2
// 925.690 us; speedup vs baseline: 1.2300x; 1.2300x over previous
//
#include <hip/hip_runtime.h>
#include <hip/hip_bf16.h>
#include <math.h>

#define NODES 50000
#define EDGES 1600000
#define HD    128
#define NC    40
#define EPSV  1e-5f

// ---------------- graph build ----------------

__global__ void k_deg(const int* __restrict__ dst, int* __restrict__ counts, int e_) {
  int e = blockIdx.x * 256 + threadIdx.x;
  if (e < e_) atomicAdd(&counts[dst[e]], 1);
}

__global__ void k_dis(const int* __restrict__ counts, float* __restrict__ dis, int n) {
  int i = blockIdx.x * 256 + threadIdx.x;
  if (i < n) dis[i] = rsqrtf((float)(counts[i] + 1));  // deg = indeg + self-loop >= 1
}

// single-block scan: row_ptr (exclusive in row_ptr[i], total in row_ptr[n]), cursor = exclusive
__global__ void k_scan(const int* __restrict__ counts, int* __restrict__ row_ptr,
                       int* __restrict__ cursor, int n) {
  __shared__ int wsum[16];
  int tid = threadIdx.x, lane = tid & 63, wid = tid >> 6;
  int running = 0;
  for (int base = 0; base < n; base += 1024) {
    int i = base + tid;
    int v = (i < n) ? counts[i] : 0;
    int x = v;
#pragma unroll
    for (int off = 1; off < 64; off <<= 1) {
      int y = __shfl_up(x, off, 64);
      if (lane >= off) x += y;
    }
    if (lane == 63) wsum[wid] = x;
    __syncthreads();
    if (wid == 0) {
      int s = (lane < 16) ? wsum[lane] : 0;
#pragma unroll
      for (int off = 1; off < 16; off <<= 1) {
        int y = __shfl_up(s, off, 64);
        if (lane >= off) s += y;
      }
      if (lane < 16) wsum[lane] = s;
    }
    __syncthreads();
    int wofs = (wid > 0) ? wsum[wid - 1] : 0;
    int incl = running + wofs + x;
    if (i < n) { row_ptr[i + 1] = incl; cursor[i] = incl - v; }
    running += wsum[15];
    __syncthreads();
  }
  if (tid == 0) row_ptr[0] = 0;
}

// fill CSR as int2 {src, w_bits}
__global__ void k_fill(const int* __restrict__ src, const int* __restrict__ dst,
                       const float* __restrict__ dis, int* __restrict__ cursor,
                       int2* __restrict__ csr_ew, int e_) {
  int e = blockIdx.x * 256 + threadIdx.x;
  if (e >= e_) return;
  int s = src[e], d = dst[e];
  int idx = atomicAdd(&cursor[d], 1);
  csr_ew[idx] = make_int2(s, __float_as_int(dis[s] * dis[d]));
}

// ---------------- fp32 GEMM: C[n,128] = A[n,128] @ B[128,128] ----------------
// 128x128 tile per 256-thread block, 8x8 register blocking, BK=64, all LDS reads b128.
__global__ __launch_bounds__(256)
void k_gemm(const float* __restrict__ A, const float* __restrict__ B,
            float* __restrict__ Cmat, int n) {
  __shared__ float As[128 * 68];   // [row][k] pad 64->68
  __shared__ float Bs[64 * 132];   // [k][col] pad 128->132
  const int tid = threadIdx.x;
  const int tx = tid & 15, ty = tid >> 4;
  const int rowBase = blockIdx.x * 128;
  const int tr = ty * 8, tc = tx * 8;
  float acc[8][8] = {};

  for (int kk = 0; kk < 128; kk += 64) {
    // stage A: 128x64 floats = 2048 float4, 8 per thread
#pragma unroll
    for (int i = 0; i < 8; ++i) {
      int f = tid + i * 256;
      int row = f >> 4;          // 16 float4 per row
      int kc = (f & 15) << 2;
      int rg = rowBase + row;
      float4 v = make_float4(0.f, 0.f, 0.f, 0.f);
      if (rg < n) v = *(const float4*)&A[(size_t)rg * 128 + kk + kc];
      *(float4*)&As[row * 68 + kc] = v;
    }
    // stage B: 64x128 floats = 2048 float4, 8 per thread
#pragma unroll
    for (int i = 0; i < 8; ++i) {
      int f = tid + i * 256;
      int k = f >> 5;            // 32 float4 per k-row
      int c = (f & 31) << 2;
      *(float4*)&Bs[k * 132 + c] = *(const float4*)&B[(size_t)(kk + k) * 128 + c];
    }
    __syncthreads();
    for (int k = 0; k < 64; k += 4) {
      float4 av[8];
#pragma unroll
      for (int i = 0; i < 8; ++i) av[i] = *(const float4*)&As[(tr + i) * 68 + k];
      float4 bv[4][2];
#pragma unroll
      for (int j = 0; j < 4; ++j) {
        bv[j][0] = *(const float4*)&Bs[(k + j) * 132 + tc];
        bv[j][1] = *(const float4*)&Bs[(k + j) * 132 + tc + 4];
      }
#pragma unroll
      for (int i = 0; i < 8; ++i) {
#pragma unroll
        for (int j = 0; j < 4; ++j) {
          float a = (&av[i].x)[j];
          acc[i][0] = fmaf(a, bv[j][0].x, acc[i][0]);
          acc[i][1] = fmaf(a, bv[j][0].y, acc[i][1]);
          acc[i][2] = fmaf(a, bv[j][0].z, acc[i][2]);
          acc[i][3] = fmaf(a, bv[j][0].w, acc[i][3]);
          acc[i][4] = fmaf(a, bv[j][1].x, acc[i][4]);
          acc[i][5] = fmaf(a, bv[j][1].y, acc[i][5]);
          acc[i][6] = fmaf(a, bv[j][1].z, acc[i][6]);
          acc[i][7] = fmaf(a, bv[j][1].w, acc[i][7]);
        }
      }
    }
    __syncthreads();
  }
#pragma unroll
  for (int i = 0; i < 8; ++i) {
    int rg = rowBase + tr + i;
    if (rg < n) {
      *(float4*)&Cmat[(size_t)rg * 128 + tc]     = make_float4(acc[i][0], acc[i][1], acc[i][2], acc[i][3]);
      *(float4*)&Cmat[(size_t)rg * 128 + tc + 4] = make_float4(acc[i][4], acc[i][5], acc[i][6], acc[i][7]);
    }
  }
}

// ---------------- aggregation: h[d] = dis[d]^2*t[d] + sum_e w_e * t[src_e] ----------------
// one wave per node; 32 lanes x float4 per edge row; 2 edges per wave-instruction;
// edge (src,w) pairs loaded cooperatively (1 coalesced int2 load per 64 edges) + shfl broadcast.
__global__ __launch_bounds__(256)
void k_agg(const float* __restrict__ t, const int* __restrict__ row_ptr,
           const int2* __restrict__ csr_ew, const float* __restrict__ dis,
           float* __restrict__ h, int n) {
  int node = (blockIdx.x * 256 + threadIdx.x) >> 6;
  if (node >= n) return;
  int lane = threadIdx.x & 63;
  int half = lane >> 5;          // which of the 2 concurrent edges
  int q4 = (lane & 31) << 2;     // feature offset (float4)
  int e0 = row_ptr[node], e1 = row_ptr[node + 1];
  float4 acc = make_float4(0.f, 0.f, 0.f, 0.f);

  for (int chunk = e0; chunk < e1; chunk += 64) {
    int m = min(64, e1 - chunk);
    int2 ev = make_int2(0, 0);
    if (lane < m) ev = csr_ew[chunk + lane];
    // 2 edges per iteration (one per half-wave), unrolled 2x -> 4 gathers in flight
#pragma unroll 2
    for (int j = 0; j < m; j += 2) {
      int jj = j + half;
      int s  = __shfl(ev.x, jj, 64);
      float w = __int_as_float(__shfl(ev.y, jj, 64));
      if (jj < m) {
        float4 v = *(const float4*)&t[(size_t)s * 128 + q4];
        acc.x = fmaf(w, v.x, acc.x);
        acc.y = fmaf(w, v.y, acc.y);
        acc.z = fmaf(w, v.z, acc.z);
        acc.w = fmaf(w, v.w, acc.w);
      }
    }
  }
  // combine the two half-wave partials
  acc.x += __shfl_xor(acc.x, 32, 64);
  acc.y += __shfl_xor(acc.y, 32, 64);
  acc.z += __shfl_xor(acc.z, 32, 64);
  acc.w += __shfl_xor(acc.w, 32, 64);
  if (half == 0) {
    float d = dis[node];
    float d2 = d * d;
    float4 sv = *(const float4*)&t[(size_t)node * 128 + q4];
    acc.x = fmaf(d2, sv.x, acc.x);
    acc.y = fmaf(d2, sv.y, acc.y);
    acc.z = fmaf(d2, sv.z, acc.z);
    acc.w = fmaf(d2, sv.w, acc.w);
    *(float4*)&h[(size_t)node * 128 + q4] = acc;
  }
}

// ---------------- BN stats: stats[f]=sum, stats[128+f]=sumsq ----------------
__global__ __launch_bounds__(256)
void k_stats(const float* __restrict__ h, float* __restrict__ stats, int n, int rows_per_block) {
  int f = threadIdx.x & 127;
  int half = threadIdx.x >> 7;  // 0..1
  int r0 = blockIdx.x * rows_per_block;
  int r1 = min(n, r0 + rows_per_block);
  float s0 = 0.f, s1 = 0.f;
  for (int r = r0 + half; r < r1; r += 2) {
    float v = h[(size_t)r * 128 + f];
    s0 += v;
    s1 += v * v;
  }
  __shared__ float l0[256], l1[256];
  l0[threadIdx.x] = s0;
  l1[threadIdx.x] = s1;
  __syncthreads();
  if (threadIdx.x < 128) {
    s0 = l0[threadIdx.x] + l0[threadIdx.x + 128];
    s1 = l1[threadIdx.x] + l1[threadIdx.x + 128];
    atomicAdd(&stats[f], s0);
    atomicAdd(&stats[128 + f], s1);
  }
}

// ---------------- BN normalize + ReLU (in place) ----------------
__global__ __launch_bounds__(256)
void k_bnrelu(float* __restrict__ h, const float* __restrict__ stats,
              const float* __restrict__ g, const float* __restrict__ be, int n) {
  int idx4 = blockIdx.x * 256 + threadIdx.x;  // float4 index
  if (idx4 >= n * 32) return;                 // n*128/4
  int f = (idx4 & 31) << 2;
  const float inv_n = 1.0f / (float)n;
  float4 v = *(float4*)&h[(size_t)idx4 * 4];
  float4 o;
#pragma unroll
  for (int j = 0; j < 4; ++j) {
    float m = stats[f + j] * inv_n;
    float var = stats[128 + f + j] * inv_n - m * m;
    float rstd = rsqrtf(var + EPSV);
    float x = ((&v.x)[j] - m) * rstd * g[f + j] + be[f + j];
    (&o.x)[j] = fmaxf(x, 0.f);
  }
  *(float4*)&h[(size_t)idx4 * 4] = o;
}

// ---------------- FC + ReLU + log_softmax: one wave per node ----------------
__global__ __launch_bounds__(256)
void k_fc(const float* __restrict__ h, const float* __restrict__ W,
          const float* __restrict__ b, float* __restrict__ out, int n) {
  int lane = threadIdx.x & 63;
  int node = (blockIdx.x * 256 + threadIdx.x) >> 6;
  if (node >= n) return;
  const float* hr = h + (size_t)node * 128;
  bool act = lane < NC;
  float acc = act ? b[lane] : 0.f;
  for (int k = 0; k < 128; ++k) {
    float a = hr[k];
    float w = act ? W[k * NC + lane] : 0.f;
    acc = fmaf(a, w, acc);
  }
  float logit = act ? fmaxf(acc, 0.f) : 0.f;
  float mv = act ? logit : -1e30f;
#pragma unroll
  for (int off = 32; off; off >>= 1) mv = fmaxf(mv, __shfl_xor(mv, off, 64));
  float ex = act ? __expf(logit - mv) : 0.f;
  float sum = ex;
#pragma unroll
  for (int off = 32; off; off >>= 1) sum += __shfl_xor(sum, off, 64);
  float lse = mv + __logf(sum);
  if (act) {
    out[(size_t)node * NC + lane] = logit - lse;
    out[(size_t)NODES * NC + (size_t)node * NC + lane] = logit;
  }
}

// ---------------- launch ----------------

extern "C" void kernel_launch(void* const* d_in, const int* in_sizes, int n_in,
                              void* d_out, int out_size, void* d_ws, size_t ws_size,
                              hipStream_t stream) {
  (void)in_sizes; (void)n_in; (void)out_size; (void)ws_size;
  const float* x   = (const float*)d_in[0];
  const int*   ei  = (const int*)d_in[1];
  const float* W1  = (const float*)d_in[2];
  const float* W2  = (const float*)d_in[4];
  const float* W3  = (const float*)d_in[6];
  const float* g1  = (const float*)d_in[8];
  const float* be1 = (const float*)d_in[9];
  const float* g2  = (const float*)d_in[10];
  const float* be2 = (const float*)d_in[11];
  const float* g3  = (const float*)d_in[12];
  const float* be3 = (const float*)d_in[13];
  const float* fcW = (const float*)d_in[14];
  const float* fcb = (const float*)d_in[15];
  float* out = (float*)d_out;

  const int n = NODES, e_ = EDGES;
  const int* srcp = ei;        // edge_index[0]
  const int* dstp = ei + e_;   // edge_index[1]

  char* ws = (char*)d_ws;
  size_t off = 0;
  auto alloc = [&](size_t bytes) {
    char* p = ws + off;
    off = (off + bytes + 255) & ~(size_t)255;
    return p;
  };
  float* dis    = (float*)alloc((size_t)n * 4);
  int*   counts = (int*)  alloc((size_t)n * 4);
  int*   row_ptr= (int*)  alloc((size_t)(n + 1) * 4);
  int*   cursor = (int*)  alloc((size_t)n * 4);
  int2*  csr_ew = (int2*) alloc((size_t)e_ * 8);
  float* tbuf   = (float*)alloc((size_t)n * HD * 4);
  float* hbuf   = (float*)alloc((size_t)n * HD * 4);
  float* stats  = (float*)alloc(256 * 4);

  hipMemsetAsync(counts, 0, (size_t)n * 4, stream);
  k_deg<<<(e_ + 255) / 256, 256, 0, stream>>>(dstp, counts, e_);
  k_dis<<<(n + 255) / 256, 256, 0, stream>>>(counts, dis, n);
  k_scan<<<1, 1024, 0, stream>>>(counts, row_ptr, cursor, n);
  k_fill<<<(e_ + 255) / 256, 256, 0, stream>>>(srcp, dstp, dis, cursor, csr_ew, e_);

  const int ggrid = (n + 127) / 128;
  const int rows_per_block = (n + 255) / 256;
  const float* in_ptr = x;
  const float* Wl[3]  = {W1, W2, W3};
  const float* gl[3]  = {g1, g2, g3};
  const float* bel[3] = {be1, be2, be3};
  for (int L = 0; L < 3; ++L) {
    k_gemm<<<ggrid, 256, 0, stream>>>(in_ptr, Wl[L], tbuf, n);
    k_agg<<<(n + 3) / 4, 256, 0, stream>>>(tbuf, row_ptr, csr_ew, dis, hbuf, n);
    hipMemsetAsync(stats, 0, 256 * 4, stream);
    k_stats<<<256, 256, 0, stream>>>(hbuf, stats, n, rows_per_block);
    k_bnrelu<<<(n * 32 + 255) / 256, 256, 0, stream>>>(hbuf, stats, gl[L], bel[L], n);
    in_ptr = hbuf;
  }
  k_fc<<<(n + 3) / 4, 256, 0, stream>>>(hbuf, fcW, fcb, out, n);
}

// Round 3
// 713.419 us; speedup vs baseline: 1.5959x; 1.2975x over previous
//
#include <hip/hip_runtime.h>
#include <hip/hip_bf16.h>
#include <math.h>

#define NODES 50000
#define EDGES 1600000
#define HD    128
#define NC    40
#define EPSV  1e-5f

typedef unsigned int uint;

// ---------------- graph build ----------------

__global__ void k_deg(const int* __restrict__ dst, int* __restrict__ counts, int e_) {
  int e = blockIdx.x * 256 + threadIdx.x;
  if (e < e_) atomicAdd(&counts[dst[e]], 1);
}

__global__ void k_dis(const int* __restrict__ counts, float* __restrict__ dis, int n) {
  int i = blockIdx.x * 256 + threadIdx.x;
  if (i < n) dis[i] = rsqrtf((float)(counts[i] + 1));  // deg = indeg + self-loop >= 1
}

// ---- 3-phase scan: per-256-block sums -> scan of sums -> per-block rescans ----
__global__ void k_scan1(const int* __restrict__ counts, int* __restrict__ bsums, int n) {
  int i = blockIdx.x * 256 + threadIdx.x;
  int v = (i < n) ? counts[i] : 0;
#pragma unroll
  for (int off = 32; off; off >>= 1) v += __shfl_down(v, off, 64);
  __shared__ int ws_[4];
  if ((threadIdx.x & 63) == 0) ws_[threadIdx.x >> 6] = v;
  __syncthreads();
  if (threadIdx.x == 0) bsums[blockIdx.x] = ws_[0] + ws_[1] + ws_[2] + ws_[3];
}

__global__ void k_scan2(const int* __restrict__ bsums, int* __restrict__ bofs, int nb) {
  __shared__ int s[256];
  int t = threadIdx.x;
  int v = (t < nb) ? bsums[t] : 0;
  s[t] = v;
  __syncthreads();
#pragma unroll
  for (int off = 1; off < 256; off <<= 1) {
    int y = (t >= off) ? s[t - off] : 0;
    __syncthreads();
    s[t] += y;
    __syncthreads();
  }
  if (t < nb) bofs[t] = s[t] - v;  // exclusive
}

__global__ void k_scan3(const int* __restrict__ counts, const int* __restrict__ bofs,
                        int* __restrict__ row_ptr, int* __restrict__ cursor, int n) {
  __shared__ int s[256];
  int t = threadIdx.x;
  int i = blockIdx.x * 256 + t;
  int v = (i < n) ? counts[i] : 0;
  s[t] = v;
  __syncthreads();
#pragma unroll
  for (int off = 1; off < 256; off <<= 1) {
    int y = (t >= off) ? s[t - off] : 0;
    __syncthreads();
    s[t] += y;
    __syncthreads();
  }
  if (i < n) {
    int incl = s[t] + bofs[blockIdx.x];
    row_ptr[i + 1] = incl;
    cursor[i] = incl - v;
    if (i == 0) row_ptr[0] = 0;
  }
}

// fill CSR as int2 {src, w_bits}
__global__ void k_fill(const int* __restrict__ src, const int* __restrict__ dst,
                       const float* __restrict__ dis, int* __restrict__ cursor,
                       int2* __restrict__ csr_ew, int e_) {
  int e = blockIdx.x * 256 + threadIdx.x;
  if (e >= e_) return;
  int s = src[e], d = dst[e];
  int idx = atomicAdd(&cursor[d], 1);
  csr_ew[idx] = make_int2(s, __float_as_int(dis[s] * dis[d]));
}

// ---------------- helpers ----------------
__device__ inline uint bfpack(float a, float b) {
  uint ua = __float_as_uint(a), ub = __float_as_uint(b);
  ua = (ua + 0x7fffu + ((ua >> 16) & 1u)) >> 16;
  ub = (ub + 0x7fffu + ((ub >> 16) & 1u)) >> 16;
  return ua | (ub << 16);
}

// ---------------- fp32 GEMM with fused BN+ReLU on A-load, bf16-packed output ----
// C_bf16[n,128] = relu(bn(A)) @ B ; 128x128 tile, 8x8 blocking, BK=64.
__global__ __launch_bounds__(256)
void k_gemm(const float* __restrict__ A, const float* __restrict__ B,
            uint* __restrict__ Cbf, int n,
            const float* __restrict__ scale, const float* __restrict__ shift) {
  __shared__ float As[128 * 68];   // [row][k] pad 64->68
  __shared__ float Bs[64 * 132];   // [k][col] pad 128->132
  const int tid = threadIdx.x;
  const int tx = tid & 15, ty = tid >> 4;
  const int rowBase = blockIdx.x * 128;
  const int tr = ty * 8, tc = tx * 8;
  float acc[8][8] = {};

  for (int kk = 0; kk < 128; kk += 64) {
#pragma unroll
    for (int i = 0; i < 8; ++i) {
      int f = tid + i * 256;
      int row = f >> 4;          // 16 float4 per row
      int kc = (f & 15) << 2;
      int rg = rowBase + row;
      float4 v = make_float4(0.f, 0.f, 0.f, 0.f);
      if (rg < n) v = *(const float4*)&A[(size_t)rg * 128 + kk + kc];
      if (scale) {
        float4 sc = *(const float4*)&scale[kk + kc];
        float4 sh = *(const float4*)&shift[kk + kc];
        v.x = fmaxf(fmaf(v.x, sc.x, sh.x), 0.f);
        v.y = fmaxf(fmaf(v.y, sc.y, sh.y), 0.f);
        v.z = fmaxf(fmaf(v.z, sc.z, sh.z), 0.f);
        v.w = fmaxf(fmaf(v.w, sc.w, sh.w), 0.f);
      }
      *(float4*)&As[row * 68 + kc] = v;
    }
#pragma unroll
    for (int i = 0; i < 8; ++i) {
      int f = tid + i * 256;
      int k = f >> 5;            // 32 float4 per k-row
      int c = (f & 31) << 2;
      *(float4*)&Bs[k * 132 + c] = *(const float4*)&B[(size_t)(kk + k) * 128 + c];
    }
    __syncthreads();
    for (int k = 0; k < 64; k += 4) {
      float4 av[8];
#pragma unroll
      for (int i = 0; i < 8; ++i) av[i] = *(const float4*)&As[(tr + i) * 68 + k];
      float4 bv[4][2];
#pragma unroll
      for (int j = 0; j < 4; ++j) {
        bv[j][0] = *(const float4*)&Bs[(k + j) * 132 + tc];
        bv[j][1] = *(const float4*)&Bs[(k + j) * 132 + tc + 4];
      }
#pragma unroll
      for (int i = 0; i < 8; ++i) {
#pragma unroll
        for (int j = 0; j < 4; ++j) {
          float a = (&av[i].x)[j];
          acc[i][0] = fmaf(a, bv[j][0].x, acc[i][0]);
          acc[i][1] = fmaf(a, bv[j][0].y, acc[i][1]);
          acc[i][2] = fmaf(a, bv[j][0].z, acc[i][2]);
          acc[i][3] = fmaf(a, bv[j][0].w, acc[i][3]);
          acc[i][4] = fmaf(a, bv[j][1].x, acc[i][4]);
          acc[i][5] = fmaf(a, bv[j][1].y, acc[i][5]);
          acc[i][6] = fmaf(a, bv[j][1].z, acc[i][6]);
          acc[i][7] = fmaf(a, bv[j][1].w, acc[i][7]);
        }
      }
    }
    __syncthreads();
  }
#pragma unroll
  for (int i = 0; i < 8; ++i) {
    int rg = rowBase + tr + i;
    if (rg < n) {
      uint4 u;
      u.x = bfpack(acc[i][0], acc[i][1]);
      u.y = bfpack(acc[i][2], acc[i][3]);
      u.z = bfpack(acc[i][4], acc[i][5]);
      u.w = bfpack(acc[i][6], acc[i][7]);
      *(uint4*)&Cbf[(size_t)rg * 64 + (tc >> 1)] = u;
    }
  }
}

// ---------------- aggregation: h[d] = dis[d]^2*t[d] + sum_e w_e * t[src_e] ----------------
// one wave per node; 16 lanes x 16B (uint4 = 8 bf16) per edge row; 4 edges per wave-instruction.
__global__ __launch_bounds__(256)
void k_agg(const uint* __restrict__ t, const int* __restrict__ row_ptr,
           const int2* __restrict__ csr_ew, const float* __restrict__ dis,
           float* __restrict__ h, int n) {
  int node = (blockIdx.x * 256 + threadIdx.x) >> 6;
  if (node >= n) return;
  int lane = threadIdx.x & 63;
  int quarter = lane >> 4;       // which of 4 concurrent edges
  int fl = lane & 15;            // 16B segment within the 256B row
  int e0 = row_ptr[node], e1 = row_ptr[node + 1];
  float acc[8] = {};

  for (int chunk = e0; chunk < e1; chunk += 64) {
    int m = min(64, e1 - chunk);
    int2 ev = make_int2(0, 0);
    if (lane < m) ev = csr_ew[chunk + lane];
#pragma unroll 4
    for (int j = 0; j < m; j += 4) {
      int jj = j + quarter;
      int s  = __shfl(ev.x, jj, 64);
      float w = __int_as_float(__shfl(ev.y, jj, 64));
      if (jj < m) {
        uint4 v = *(const uint4*)&t[(size_t)s * 64 + (fl << 2)];
        acc[0] = fmaf(w, __uint_as_float(v.x << 16), acc[0]);
        acc[1] = fmaf(w, __uint_as_float(v.x & 0xffff0000u), acc[1]);
        acc[2] = fmaf(w, __uint_as_float(v.y << 16), acc[2]);
        acc[3] = fmaf(w, __uint_as_float(v.y & 0xffff0000u), acc[3]);
        acc[4] = fmaf(w, __uint_as_float(v.z << 16), acc[4]);
        acc[5] = fmaf(w, __uint_as_float(v.z & 0xffff0000u), acc[5]);
        acc[6] = fmaf(w, __uint_as_float(v.w << 16), acc[6]);
        acc[7] = fmaf(w, __uint_as_float(v.w & 0xffff0000u), acc[7]);
      }
    }
  }
#pragma unroll
  for (int j = 0; j < 8; ++j) {
    acc[j] += __shfl_xor(acc[j], 16, 64);
    acc[j] += __shfl_xor(acc[j], 32, 64);
  }
  if (quarter == 0) {
    float d = dis[node];
    float d2 = d * d;
    uint4 v = *(const uint4*)&t[(size_t)node * 64 + (fl << 2)];
    acc[0] = fmaf(d2, __uint_as_float(v.x << 16), acc[0]);
    acc[1] = fmaf(d2, __uint_as_float(v.x & 0xffff0000u), acc[1]);
    acc[2] = fmaf(d2, __uint_as_float(v.y << 16), acc[2]);
    acc[3] = fmaf(d2, __uint_as_float(v.y & 0xffff0000u), acc[3]);
    acc[4] = fmaf(d2, __uint_as_float(v.z << 16), acc[4]);
    acc[5] = fmaf(d2, __uint_as_float(v.z & 0xffff0000u), acc[5]);
    acc[6] = fmaf(d2, __uint_as_float(v.w << 16), acc[6]);
    acc[7] = fmaf(d2, __uint_as_float(v.w & 0xffff0000u), acc[7]);
    *(float4*)&h[(size_t)node * 128 + (fl << 3)]     = make_float4(acc[0], acc[1], acc[2], acc[3]);
    *(float4*)&h[(size_t)node * 128 + (fl << 3) + 4] = make_float4(acc[4], acc[5], acc[6], acc[7]);
  }
}

// ---------------- BN stats: stats[f]=sum, stats[128+f]=sumsq ----------------
__global__ __launch_bounds__(256)
void k_stats(const float* __restrict__ h, float* __restrict__ stats, int n, int rows_per_block) {
  int f = threadIdx.x & 127;
  int half = threadIdx.x >> 7;  // 0..1
  int r0 = blockIdx.x * rows_per_block;
  int r1 = min(n, r0 + rows_per_block);
  float s0 = 0.f, s1 = 0.f;
  for (int r = r0 + half; r < r1; r += 2) {
    float v = h[(size_t)r * 128 + f];
    s0 += v;
    s1 += v * v;
  }
  __shared__ float l0[256], l1[256];
  l0[threadIdx.x] = s0;
  l1[threadIdx.x] = s1;
  __syncthreads();
  if (threadIdx.x < 128) {
    s0 = l0[threadIdx.x] + l0[threadIdx.x + 128];
    s1 = l1[threadIdx.x] + l1[threadIdx.x + 128];
    atomicAdd(&stats[f], s0);
    atomicAdd(&stats[128 + f], s1);
  }
}

// ---------------- BN params: scale = g*rstd, shift = be - m*scale ----------------
__global__ void k_bnparams(const float* __restrict__ stats, const float* __restrict__ g,
                           const float* __restrict__ be, float* __restrict__ scale,
                           float* __restrict__ shift, int n) {
  int f = threadIdx.x;  // 128
  float inv_n = 1.0f / (float)n;
  float m = stats[f] * inv_n;
  float var = stats[128 + f] * inv_n - m * m;
  float rstd = rsqrtf(var + EPSV);
  float sc = g[f] * rstd;
  scale[f] = sc;
  shift[f] = be[f] - m * sc;
}

// ---------------- FC(+fused BN/ReLU on input) + ReLU + log_softmax ----------------
__global__ __launch_bounds__(256)
void k_fc(const float* __restrict__ h, const float* __restrict__ scale,
          const float* __restrict__ shift, const float* __restrict__ W,
          const float* __restrict__ b, float* __restrict__ out, int n) {
  int lane = threadIdx.x & 63;
  int node = (blockIdx.x * 256 + threadIdx.x) >> 6;
  if (node >= n) return;
  const float* hr = h + (size_t)node * 128;
  bool act = lane < NC;
  float acc = act ? b[lane] : 0.f;
  for (int k = 0; k < 128; ++k) {
    float a = fmaxf(fmaf(hr[k], scale[k], shift[k]), 0.f);
    float w = act ? W[k * NC + lane] : 0.f;
    acc = fmaf(a, w, acc);
  }
  float logit = act ? fmaxf(acc, 0.f) : 0.f;
  float mv = act ? logit : -1e30f;
#pragma unroll
  for (int off = 32; off; off >>= 1) mv = fmaxf(mv, __shfl_xor(mv, off, 64));
  float ex = act ? __expf(logit - mv) : 0.f;
  float sum = ex;
#pragma unroll
  for (int off = 32; off; off >>= 1) sum += __shfl_xor(sum, off, 64);
  float lse = mv + __logf(sum);
  if (act) {
    out[(size_t)node * NC + lane] = logit - lse;
    out[(size_t)NODES * NC + (size_t)node * NC + lane] = logit;
  }
}

// ---------------- launch ----------------

extern "C" void kernel_launch(void* const* d_in, const int* in_sizes, int n_in,
                              void* d_out, int out_size, void* d_ws, size_t ws_size,
                              hipStream_t stream) {
  (void)in_sizes; (void)n_in; (void)out_size; (void)ws_size;
  const float* x   = (const float*)d_in[0];
  const int*   ei  = (const int*)d_in[1];
  const float* W1  = (const float*)d_in[2];
  const float* W2  = (const float*)d_in[4];
  const float* W3  = (const float*)d_in[6];
  const float* g1  = (const float*)d_in[8];
  const float* be1 = (const float*)d_in[9];
  const float* g2  = (const float*)d_in[10];
  const float* be2 = (const float*)d_in[11];
  const float* g3  = (const float*)d_in[12];
  const float* be3 = (const float*)d_in[13];
  const float* fcW = (const float*)d_in[14];
  const float* fcb = (const float*)d_in[15];
  float* out = (float*)d_out;

  const int n = NODES, e_ = EDGES;
  const int* srcp = ei;        // edge_index[0]
  const int* dstp = ei + e_;   // edge_index[1]
  const int nb = (n + 255) / 256;

  char* ws = (char*)d_ws;
  size_t off = 0;
  auto alloc = [&](size_t bytes) {
    char* p = ws + off;
    off = (off + bytes + 255) & ~(size_t)255;
    return p;
  };
  float* dis    = (float*)alloc((size_t)n * 4);
  int*   counts = (int*)  alloc((size_t)n * 4);
  int*   row_ptr= (int*)  alloc((size_t)(n + 1) * 4);
  int*   cursor = (int*)  alloc((size_t)n * 4);
  int*   bsums  = (int*)  alloc((size_t)nb * 4);
  int*   bofs   = (int*)  alloc((size_t)nb * 4);
  int2*  csr_ew = (int2*) alloc((size_t)e_ * 8);
  uint*  tbuf   = (uint*) alloc((size_t)n * 64 * 4);   // bf16-packed [n,128]
  float* hbuf   = (float*)alloc((size_t)n * HD * 4);
  float* stats  = (float*)alloc(256 * 4);
  float* scale  = (float*)alloc(128 * 4);
  float* shift  = (float*)alloc(128 * 4);

  hipMemsetAsync(counts, 0, (size_t)n * 4, stream);
  k_deg<<<(e_ + 255) / 256, 256, 0, stream>>>(dstp, counts, e_);
  k_dis<<<nb, 256, 0, stream>>>(counts, dis, n);
  k_scan1<<<nb, 256, 0, stream>>>(counts, bsums, n);
  k_scan2<<<1, 256, 0, stream>>>(bsums, bofs, nb);
  k_scan3<<<nb, 256, 0, stream>>>(counts, bofs, row_ptr, cursor, n);
  k_fill<<<(e_ + 255) / 256, 256, 0, stream>>>(srcp, dstp, dis, cursor, csr_ew, e_);

  const int ggrid = (n + 127) / 128;
  const int rows_per_block = (n + 255) / 256;
  const float* in_ptr = x;
  const float* Wl[3]  = {W1, W2, W3};
  const float* gl[3]  = {g1, g2, g3};
  const float* bel[3] = {be1, be2, be3};
  for (int L = 0; L < 3; ++L) {
    k_gemm<<<ggrid, 256, 0, stream>>>(in_ptr, Wl[L], tbuf, n,
                                      L == 0 ? nullptr : scale, L == 0 ? nullptr : shift);
    k_agg<<<(n + 3) / 4, 256, 0, stream>>>(tbuf, row_ptr, csr_ew, dis, hbuf, n);
    hipMemsetAsync(stats, 0, 256 * 4, stream);
    k_stats<<<256, 256, 0, stream>>>(hbuf, stats, n, rows_per_block);
    k_bnparams<<<1, 128, 0, stream>>>(stats, gl[L], bel[L], scale, shift, n);
    in_ptr = hbuf;
  }
  k_fc<<<(n + 3) / 4, 256, 0, stream>>>(hbuf, scale, shift, fcW, fcb, out, n);
}

// Round 4
// 611.143 us; speedup vs baseline: 1.8630x; 1.1674x over previous
//
#include <hip/hip_runtime.h>
#include <hip/hip_bf16.h>
#include <math.h>

#define NODES 50000
#define EDGES 1600000
#define HD    128
#define NC    40
#define EPSV  1e-5f

typedef unsigned int uint;
typedef unsigned short ushort;
typedef __attribute__((ext_vector_type(8))) short bfrag;
typedef __attribute__((ext_vector_type(4))) float ffrag;

union FragU { uint4 u; bfrag f; };

__device__ inline ushort bf1(float x) {
  uint u = __float_as_uint(x);
  return (ushort)((u + 0x7fffu + ((u >> 16) & 1u)) >> 16);
}
__device__ inline uint bf2(float a, float b) {
  return (uint)bf1(a) | ((uint)bf1(b) << 16);
}
__device__ inline float ulo(uint u) { return __uint_as_float(u << 16); }
__device__ inline float uhi(uint u) { return __uint_as_float(u & 0xffff0000u); }

// ---------------- graph build ----------------

__global__ void k_deg(const int* __restrict__ dst, int* __restrict__ counts, int e_) {
  int e = blockIdx.x * 256 + threadIdx.x;
  if (e < e_) atomicAdd(&counts[dst[e]], 1);
}

__global__ void k_dis(const int* __restrict__ counts, float* __restrict__ dis, int n) {
  int i = blockIdx.x * 256 + threadIdx.x;
  if (i < n) dis[i] = rsqrtf((float)(counts[i] + 1));  // deg = indeg + self-loop >= 1
}

// ---- 3-phase scan ----
__global__ void k_scan1(const int* __restrict__ counts, int* __restrict__ bsums, int n) {
  int i = blockIdx.x * 256 + threadIdx.x;
  int v = (i < n) ? counts[i] : 0;
#pragma unroll
  for (int off = 32; off; off >>= 1) v += __shfl_down(v, off, 64);
  __shared__ int ws_[4];
  if ((threadIdx.x & 63) == 0) ws_[threadIdx.x >> 6] = v;
  __syncthreads();
  if (threadIdx.x == 0) bsums[blockIdx.x] = ws_[0] + ws_[1] + ws_[2] + ws_[3];
}

__global__ void k_scan2(const int* __restrict__ bsums, int* __restrict__ bofs, int nb) {
  __shared__ int s[256];
  int t = threadIdx.x;
  int v = (t < nb) ? bsums[t] : 0;
  s[t] = v;
  __syncthreads();
#pragma unroll
  for (int off = 1; off < 256; off <<= 1) {
    int y = (t >= off) ? s[t - off] : 0;
    __syncthreads();
    s[t] += y;
    __syncthreads();
  }
  if (t < nb) bofs[t] = s[t] - v;  // exclusive
}

__global__ void k_scan3(const int* __restrict__ counts, const int* __restrict__ bofs,
                        int* __restrict__ row_ptr, int* __restrict__ cursor, int n) {
  __shared__ int s[256];
  int t = threadIdx.x;
  int i = blockIdx.x * 256 + t;
  int v = (i < n) ? counts[i] : 0;
  s[t] = v;
  __syncthreads();
#pragma unroll
  for (int off = 1; off < 256; off <<= 1) {
    int y = (t >= off) ? s[t - off] : 0;
    __syncthreads();
    s[t] += y;
    __syncthreads();
  }
  if (i < n) {
    int incl = s[t] + bofs[blockIdx.x];
    row_ptr[i + 1] = incl;
    cursor[i] = incl - v;
    if (i == 0) row_ptr[0] = 0;
  }
}

// fill CSR as int2 {src, w_bits}
__global__ void k_fill(const int* __restrict__ src, const int* __restrict__ dst,
                       const float* __restrict__ dis, int* __restrict__ cursor,
                       int2* __restrict__ csr_ew, int e_) {
  int e = blockIdx.x * 256 + threadIdx.x;
  if (e >= e_) return;
  int s = src[e], d = dst[e];
  int idx = atomicAdd(&cursor[d], 1);
  csr_ew[idx] = make_int2(s, __float_as_int(dis[s] * dis[d]));
}

// ---------------- weight prep: Wt[n][k] bf16 for W1,W2,W3 + fcW (pad 40->48) ----
// regions in ushorts: [0,16384) Wt1, [16384,32768) Wt2, [32768,49152) Wt3, [49152,55296) fcWt
__global__ void k_prepw(const float* __restrict__ W1, const float* __restrict__ W2,
                        const float* __restrict__ W3, const float* __restrict__ fcW,
                        ushort* __restrict__ wt) {
  int idx = blockIdx.x * 256 + threadIdx.x;
  if (idx < 49152) {
    int r = idx >> 14;
    int i = idx & 16383;
    int nn = i >> 7, k = i & 127;
    const float* W = (r == 0) ? W1 : ((r == 1) ? W2 : W3);
    wt[idx] = bf1(W[k * 128 + nn]);
  } else if (idx < 55296) {
    int i = idx - 49152;
    int nn = i >> 7, k = i & 127;
    wt[idx] = (nn < NC) ? bf1(fcW[k * NC + nn]) : (ushort)0;
  }
}

// ---------------- MFMA GEMM: C_bf16[n,128] = relu(bn(A)) @ W ----------------
// block 256 = 4 waves; wave owns 16 rows x 128 cols; K=128 in 4 steps of 32.
// BF16IN=0: A fp32, no BN (layer 1). BF16IN=1: A packed bf16 + scale/shift + relu.
template<int BF16IN>
__global__ __launch_bounds__(256)
void k_gemm_mx(const void* __restrict__ Ain, const uint* __restrict__ Wt,
               ushort* __restrict__ Cb, int n,
               const float* __restrict__ scale, const float* __restrict__ shift) {
  const int lane = threadIdx.x & 63;
  const int wave = threadIdx.x >> 6;
  const int quad = lane >> 4;
  const int ml = lane & 15;
  const int row0 = blockIdx.x * 64 + wave * 16;
  const int arow = row0 + ml;
  ffrag acc[8];
#pragma unroll
  for (int i = 0; i < 8; ++i) acc[i] = (ffrag){0.f, 0.f, 0.f, 0.f};

#pragma unroll
  for (int s = 0; s < 4; ++s) {
    const int k0 = s * 32 + quad * 8;
    FragU a;
    if (arow < n) {
      if (BF16IN) {
        const uint* Ab = (const uint*)Ain;
        uint4 v = *(const uint4*)&Ab[(size_t)arow * 64 + (k0 >> 1)];
        float4 sc0 = *(const float4*)&scale[k0];
        float4 sc1 = *(const float4*)&scale[k0 + 4];
        float4 sh0 = *(const float4*)&shift[k0];
        float4 sh1 = *(const float4*)&shift[k0 + 4];
        a.u.x = bf2(fmaxf(fmaf(ulo(v.x), sc0.x, sh0.x), 0.f), fmaxf(fmaf(uhi(v.x), sc0.y, sh0.y), 0.f));
        a.u.y = bf2(fmaxf(fmaf(ulo(v.y), sc0.z, sh0.z), 0.f), fmaxf(fmaf(uhi(v.y), sc0.w, sh0.w), 0.f));
        a.u.z = bf2(fmaxf(fmaf(ulo(v.z), sc1.x, sh1.x), 0.f), fmaxf(fmaf(uhi(v.z), sc1.y, sh1.y), 0.f));
        a.u.w = bf2(fmaxf(fmaf(ulo(v.w), sc1.z, sh1.z), 0.f), fmaxf(fmaf(uhi(v.w), sc1.w, sh1.w), 0.f));
      } else {
        const float* Af = (const float*)Ain;
        float4 a0 = *(const float4*)&Af[(size_t)arow * 128 + k0];
        float4 a1 = *(const float4*)&Af[(size_t)arow * 128 + k0 + 4];
        a.u.x = bf2(a0.x, a0.y);
        a.u.y = bf2(a0.z, a0.w);
        a.u.z = bf2(a1.x, a1.y);
        a.u.w = bf2(a1.z, a1.w);
      }
    } else {
      a.u = make_uint4(0, 0, 0, 0);
    }
#pragma unroll
    for (int nt = 0; nt < 8; ++nt) {
      FragU b;
      b.u = *(const uint4*)&Wt[(size_t)(nt * 16 + ml) * 64 + (k0 >> 1)];
      acc[nt] = __builtin_amdgcn_mfma_f32_16x16x32_bf16(a.f, b.f, acc[nt], 0, 0, 0);
    }
  }
#pragma unroll
  for (int nt = 0; nt < 8; ++nt) {
#pragma unroll
    for (int r = 0; r < 4; ++r) {
      int orow = row0 + quad * 4 + r;
      if (orow < n) Cb[(size_t)orow * 128 + nt * 16 + ml] = bf1(acc[nt][r]);
    }
  }
}

// ---------------- aggregation: hb[d] = bf16( dis[d]^2*t[d] + sum_e w_e * t[src_e] ) ----
__global__ __launch_bounds__(256)
void k_agg(const uint* __restrict__ t, const int* __restrict__ row_ptr,
           const int2* __restrict__ csr_ew, const float* __restrict__ dis,
           uint* __restrict__ hb, int n) {
  int node = (blockIdx.x * 256 + threadIdx.x) >> 6;
  if (node >= n) return;
  int lane = threadIdx.x & 63;
  int quarter = lane >> 4;       // which of 4 concurrent edges
  int fl = lane & 15;            // 16B segment within the 256B row
  int e0 = row_ptr[node], e1 = row_ptr[node + 1];
  float acc[8] = {};

  for (int chunk = e0; chunk < e1; chunk += 64) {
    int m = min(64, e1 - chunk);
    int2 ev = make_int2(0, 0);
    if (lane < m) ev = csr_ew[chunk + lane];
#pragma unroll 4
    for (int j = 0; j < m; j += 4) {
      int jj = j + quarter;
      int s  = __shfl(ev.x, jj, 64);
      float w = __int_as_float(__shfl(ev.y, jj, 64));
      if (jj < m) {
        uint4 v = *(const uint4*)&t[(size_t)s * 64 + (fl << 2)];
        acc[0] = fmaf(w, ulo(v.x), acc[0]);
        acc[1] = fmaf(w, uhi(v.x), acc[1]);
        acc[2] = fmaf(w, ulo(v.y), acc[2]);
        acc[3] = fmaf(w, uhi(v.y), acc[3]);
        acc[4] = fmaf(w, ulo(v.z), acc[4]);
        acc[5] = fmaf(w, uhi(v.z), acc[5]);
        acc[6] = fmaf(w, ulo(v.w), acc[6]);
        acc[7] = fmaf(w, uhi(v.w), acc[7]);
      }
    }
  }
#pragma unroll
  for (int j = 0; j < 8; ++j) {
    acc[j] += __shfl_xor(acc[j], 16, 64);
    acc[j] += __shfl_xor(acc[j], 32, 64);
  }
  if (quarter == 0) {
    float d = dis[node];
    float d2 = d * d;
    uint4 v = *(const uint4*)&t[(size_t)node * 64 + (fl << 2)];
    acc[0] = fmaf(d2, ulo(v.x), acc[0]);
    acc[1] = fmaf(d2, uhi(v.x), acc[1]);
    acc[2] = fmaf(d2, ulo(v.y), acc[2]);
    acc[3] = fmaf(d2, uhi(v.y), acc[3]);
    acc[4] = fmaf(d2, ulo(v.z), acc[4]);
    acc[5] = fmaf(d2, uhi(v.z), acc[5]);
    acc[6] = fmaf(d2, ulo(v.w), acc[6]);
    acc[7] = fmaf(d2, uhi(v.w), acc[7]);
    uint4 o;
    o.x = bf2(acc[0], acc[1]);
    o.y = bf2(acc[2], acc[3]);
    o.z = bf2(acc[4], acc[5]);
    o.w = bf2(acc[6], acc[7]);
    *(uint4*)&hb[(size_t)node * 64 + (fl << 2)] = o;
  }
}

// ---------------- BN stats over bf16 hb: stats[f]=sum, stats[128+f]=sumsq ----
__global__ __launch_bounds__(256)
void k_stats(const uint* __restrict__ hb, float* __restrict__ stats, int n, int rpb) {
  int f2 = threadIdx.x & 63;   // feature pair
  int q  = threadIdx.x >> 6;   // 0..3 row phase
  int r0 = blockIdx.x * rpb, r1 = min(n, r0 + rpb);
  float sa = 0.f, qa = 0.f, sb = 0.f, qb = 0.f;
  for (int r = r0 + q; r < r1; r += 4) {
    uint u = hb[(size_t)r * 64 + f2];
    float a = ulo(u), b = uhi(u);
    sa += a; qa += a * a; sb += b; qb += b * b;
  }
  __shared__ float4 red[256];
  red[threadIdx.x] = make_float4(sa, qa, sb, qb);
  __syncthreads();
  if (q == 0) {
    float4 v0 = red[f2], v1 = red[64 + f2], v2 = red[128 + f2], v3 = red[192 + f2];
    atomicAdd(&stats[2 * f2],       v0.x + v1.x + v2.x + v3.x);
    atomicAdd(&stats[2 * f2 + 1],   v0.z + v1.z + v2.z + v3.z);
    atomicAdd(&stats[128 + 2 * f2], v0.y + v1.y + v2.y + v3.y);
    atomicAdd(&stats[129 + 2 * f2], v0.w + v1.w + v2.w + v3.w);
  }
}

// ---------------- BN params: scale = g*rstd, shift = be - m*scale ----------------
__global__ void k_bnparams(const float* __restrict__ stats, const float* __restrict__ g,
                           const float* __restrict__ be, float* __restrict__ scale,
                           float* __restrict__ shift, int n) {
  int f = threadIdx.x;  // 128
  float inv_n = 1.0f / (float)n;
  float m = stats[f] * inv_n;
  float var = stats[128 + f] * inv_n - m * m;
  float rstd = rsqrtf(var + EPSV);
  float sc = g[f] * rstd;
  scale[f] = sc;
  shift[f] = be[f] - m * sc;
}

// ---------------- MFMA FC + ReLU + log_softmax ----------------
// wave owns 16 rows x 48 cols (40 valid); K=128 in 4 steps; softmax within quad.
__global__ __launch_bounds__(256)
void k_fc_mx(const uint* __restrict__ hb, const float* __restrict__ scale,
             const float* __restrict__ shift, const uint* __restrict__ fWt,
             const float* __restrict__ fcb, float* __restrict__ out, int n) {
  const int lane = threadIdx.x & 63;
  const int wave = threadIdx.x >> 6;
  const int quad = lane >> 4;
  const int ml = lane & 15;
  const int row0 = blockIdx.x * 64 + wave * 16;
  const int arow = row0 + ml;
  ffrag acc[3];
#pragma unroll
  for (int i = 0; i < 3; ++i) acc[i] = (ffrag){0.f, 0.f, 0.f, 0.f};

#pragma unroll
  for (int s = 0; s < 4; ++s) {
    const int k0 = s * 32 + quad * 8;
    FragU a;
    if (arow < n) {
      uint4 v = *(const uint4*)&hb[(size_t)arow * 64 + (k0 >> 1)];
      float4 sc0 = *(const float4*)&scale[k0];
      float4 sc1 = *(const float4*)&scale[k0 + 4];
      float4 sh0 = *(const float4*)&shift[k0];
      float4 sh1 = *(const float4*)&shift[k0 + 4];
      a.u.x = bf2(fmaxf(fmaf(ulo(v.x), sc0.x, sh0.x), 0.f), fmaxf(fmaf(uhi(v.x), sc0.y, sh0.y), 0.f));
      a.u.y = bf2(fmaxf(fmaf(ulo(v.y), sc0.z, sh0.z), 0.f), fmaxf(fmaf(uhi(v.y), sc0.w, sh0.w), 0.f));
      a.u.z = bf2(fmaxf(fmaf(ulo(v.z), sc1.x, sh1.x), 0.f), fmaxf(fmaf(uhi(v.z), sc1.y, sh1.y), 0.f));
      a.u.w = bf2(fmaxf(fmaf(ulo(v.w), sc1.z, sh1.z), 0.f), fmaxf(fmaf(uhi(v.w), sc1.w, sh1.w), 0.f));
    } else {
      a.u = make_uint4(0, 0, 0, 0);
    }
#pragma unroll
    for (int nt = 0; nt < 3; ++nt) {
      FragU b;
      b.u = *(const uint4*)&fWt[(size_t)(nt * 16 + ml) * 64 + (k0 >> 1)];
      acc[nt] = __builtin_amdgcn_mfma_f32_16x16x32_bf16(a.f, b.f, acc[nt], 0, 0, 0);
    }
  }

  float b0 = fcb[ml], b1 = fcb[16 + ml];
  float b2 = (ml < 8) ? fcb[32 + ml] : 0.f;
#pragma unroll
  for (int r = 0; r < 4; ++r) {
    int orow = row0 + quad * 4 + r;
    if (orow >= n) continue;
    float l0 = fmaxf(acc[0][r] + b0, 0.f);
    float l1 = fmaxf(acc[1][r] + b1, 0.f);
    float l2 = (ml < 8) ? fmaxf(acc[2][r] + b2, 0.f) : -1e30f;
    float mx = fmaxf(fmaxf(l0, l1), l2);
#pragma unroll
    for (int off = 1; off < 16; off <<= 1) mx = fmaxf(mx, __shfl_xor(mx, off, 64));
    float sm = __expf(l0 - mx) + __expf(l1 - mx) + ((ml < 8) ? __expf(l2 - mx) : 0.f);
#pragma unroll
    for (int off = 1; off < 16; off <<= 1) sm += __shfl_xor(sm, off, 64);
    float lse = mx + __logf(sm);
    float* o1 = out + (size_t)orow * NC;
    float* o2 = out + (size_t)NODES * NC + (size_t)orow * NC;
    o1[ml] = l0 - lse;
    o1[16 + ml] = l1 - lse;
    o2[ml] = l0;
    o2[16 + ml] = l1;
    if (ml < 8) {
      o1[32 + ml] = l2 - lse;
      o2[32 + ml] = l2;
    }
  }
}

// ---------------- launch ----------------

extern "C" void kernel_launch(void* const* d_in, const int* in_sizes, int n_in,
                              void* d_out, int out_size, void* d_ws, size_t ws_size,
                              hipStream_t stream) {
  (void)in_sizes; (void)n_in; (void)out_size; (void)ws_size;
  const float* x   = (const float*)d_in[0];
  const int*   ei  = (const int*)d_in[1];
  const float* W1  = (const float*)d_in[2];
  const float* W2  = (const float*)d_in[4];
  const float* W3  = (const float*)d_in[6];
  const float* g1  = (const float*)d_in[8];
  const float* be1 = (const float*)d_in[9];
  const float* g2  = (const float*)d_in[10];
  const float* be2 = (const float*)d_in[11];
  const float* g3  = (const float*)d_in[12];
  const float* be3 = (const float*)d_in[13];
  const float* fcW = (const float*)d_in[14];
  const float* fcb = (const float*)d_in[15];
  float* out = (float*)d_out;

  const int n = NODES, e_ = EDGES;
  const int* srcp = ei;        // edge_index[0]
  const int* dstp = ei + e_;   // edge_index[1]
  const int nb = (n + 255) / 256;

  char* ws = (char*)d_ws;
  size_t off = 0;
  auto alloc = [&](size_t bytes) {
    char* p = ws + off;
    off = (off + bytes + 255) & ~(size_t)255;
    return p;
  };
  float* dis    = (float*)alloc((size_t)n * 4);
  int*   counts = (int*)  alloc((size_t)n * 4);
  int*   row_ptr= (int*)  alloc((size_t)(n + 1) * 4);
  int*   cursor = (int*)  alloc((size_t)n * 4);
  int*   bsums  = (int*)  alloc((size_t)nb * 4);
  int*   bofs   = (int*)  alloc((size_t)nb * 4);
  int2*  csr_ew = (int2*) alloc((size_t)e_ * 8);
  uint*  tbuf   = (uint*) alloc((size_t)n * 64 * 4);   // bf16-packed [n,128]
  uint*  hbuf   = (uint*) alloc((size_t)n * 64 * 4);   // bf16-packed [n,128]
  ushort* wbuf  = (ushort*)alloc(55296 * 2);           // Wt1,Wt2,Wt3,fcWt
  float* stats  = (float*)alloc(256 * 4);
  float* scale  = (float*)alloc(128 * 4);
  float* shift  = (float*)alloc(128 * 4);

  const uint* Wt1  = (const uint*)wbuf;
  const uint* Wt2  = (const uint*)wbuf + 8192;
  const uint* Wt3  = (const uint*)wbuf + 16384;
  const uint* fWt  = (const uint*)wbuf + 24576;

  hipMemsetAsync(counts, 0, (size_t)n * 4, stream);
  k_deg<<<(e_ + 255) / 256, 256, 0, stream>>>(dstp, counts, e_);
  k_dis<<<nb, 256, 0, stream>>>(counts, dis, n);
  k_scan1<<<nb, 256, 0, stream>>>(counts, bsums, n);
  k_scan2<<<1, 256, 0, stream>>>(bsums, bofs, nb);
  k_scan3<<<nb, 256, 0, stream>>>(counts, bofs, row_ptr, cursor, n);
  k_fill<<<(e_ + 255) / 256, 256, 0, stream>>>(srcp, dstp, dis, cursor, csr_ew, e_);
  k_prepw<<<216, 256, 0, stream>>>(W1, W2, W3, fcW, wbuf);

  const int ggrid = (n + 63) / 64;      // 782
  const int srpb  = (n + 127) / 128;    // 391
  const uint* Wts[3] = {Wt1, Wt2, Wt3};
  const float* gl[3]  = {g1, g2, g3};
  const float* bel[3] = {be1, be2, be3};

  for (int L = 0; L < 3; ++L) {
    if (L == 0)
      k_gemm_mx<0><<<ggrid, 256, 0, stream>>>(x, Wts[L], (ushort*)tbuf, n, nullptr, nullptr);
    else
      k_gemm_mx<1><<<ggrid, 256, 0, stream>>>(hbuf, Wts[L], (ushort*)tbuf, n, scale, shift);
    k_agg<<<(n + 3) / 4, 256, 0, stream>>>(tbuf, row_ptr, csr_ew, dis, hbuf, n);
    hipMemsetAsync(stats, 0, 256 * 4, stream);
    k_stats<<<128, 256, 0, stream>>>(hbuf, stats, n, srpb);
    k_bnparams<<<1, 128, 0, stream>>>(stats, gl[L], bel[L], scale, shift, n);
  }
  k_fc_mx<<<ggrid, 256, 0, stream>>>(hbuf, scale, shift, fWt, fcb, out, n);
}

// Round 5
// 489.464 us; speedup vs baseline: 2.3262x; 1.2486x over previous
//
#include <hip/hip_runtime.h>
#include <hip/hip_bf16.h>
#include <math.h>

#define NODES 50000
#define EDGES 1600000
#define HD    128
#define NC    40
#define EPSV  1e-5f
#define NBKT  196           // ceil(50000/256)
#define CSRMAX 12032        // per-bucket staging cap (mean 8192, sd ~90)

typedef unsigned int uint;
typedef unsigned short ushort;
typedef __attribute__((ext_vector_type(8))) short bfrag;
typedef __attribute__((ext_vector_type(4))) float ffrag;

union FragU { uint4 u; bfrag f; };

__device__ inline ushort bf1(float x) {
  uint u = __float_as_uint(x);
  return (ushort)((u + 0x7fffu + ((u >> 16) & 1u)) >> 16);
}
__device__ inline uint bf2(float a, float b) {
  return (uint)bf1(a) | ((uint)bf1(b) << 16);
}
__device__ inline float ulo(uint u) { return __uint_as_float(u << 16); }
__device__ inline float uhi(uint u) { return __uint_as_float(u & 0xffff0000u); }

// ---------------- graph build: bucket-binned, coalesced-write CSR ----------------

// per-block LDS histogram of dst>>8, flush to global bucket counts
__global__ __launch_bounds__(256)
void k_bcount(const int* __restrict__ dst, int* __restrict__ bcnt, int e_) {
  __shared__ int h[256];
  int t = threadIdx.x;
  h[t] = 0;
  __syncthreads();
  int base = blockIdx.x * 8192;
  int cntE = min(8192, e_ - base);
  for (int i = t; i < cntE; i += 256) atomicAdd(&h[dst[base + i] >> 8], 1);
  __syncthreads();
  if (h[t]) atomicAdd(&bcnt[t], h[t]);
}

// scan bucket counts -> bases & cursors; also row_ptr[n] = E
__global__ void k_bscan(const int* __restrict__ bcnt, int* __restrict__ bbase,
                        int* __restrict__ bcur, int* __restrict__ row_ptr) {
  __shared__ int s[256];
  int t = threadIdx.x;
  int v = bcnt[t];
  s[t] = v;
  __syncthreads();
#pragma unroll
  for (int off = 1; off < 256; off <<= 1) {
    int y = (t >= off) ? s[t - off] : 0;
    __syncthreads();
    s[t] += y;
    __syncthreads();
  }
  int excl = s[t] - v;
  bbase[t] = excl;
  bcur[t] = excl;
  if (t == 255) {
    bbase[256] = s[255];
    row_ptr[NODES] = s[255];
  }
}

// group 8192 edges by bucket in LDS, reserve a burst per bucket, coalesced copy out.
// staged entry: src(0:15) | dstLow(16:23) | bucket(24:31)
__global__ __launch_bounds__(256)
void k_bin(const int* __restrict__ src, const int* __restrict__ dst,
           int* __restrict__ bcur, uint* __restrict__ staging, int e_) {
  __shared__ uint ent[8192];
  __shared__ int h[256], inc[256], lofs[256], cur[256], gb[256];
  int t = threadIdx.x;
  h[t] = 0;
  __syncthreads();
  int base = blockIdx.x * 8192;
  int cntE = min(8192, e_ - base);
  for (int i = t; i < cntE; i += 256) atomicAdd(&h[dst[base + i] >> 8], 1);
  __syncthreads();
  inc[t] = h[t];
  __syncthreads();
#pragma unroll
  for (int off = 1; off < 256; off <<= 1) {
    int y = (t >= off) ? inc[t - off] : 0;
    __syncthreads();
    inc[t] += y;
    __syncthreads();
  }
  lofs[t] = inc[t] - h[t];
  cur[t] = 0;
  __syncthreads();
  for (int i = t; i < cntE; i += 256) {
    int e = base + i;
    int d = dst[e];
    int b = d >> 8;
    uint en = (uint)(src[e] & 0xffff) | ((uint)(d & 255) << 16) | ((uint)b << 24);
    int p = lofs[b] + atomicAdd(&cur[b], 1);
    ent[p] = en;
  }
  __syncthreads();
  if (h[t]) gb[t] = atomicAdd(&bcur[t], h[t]);
  __syncthreads();
  for (int i = t; i < cntE; i += 256) {
    uint en = ent[i];
    int b = en >> 24;
    staging[gb[b] + (i - lofs[b])] = en;
  }
}

// one block per bucket: counting-sort by dstLow in LDS, coalesced u16 CSR write,
// row_ptr + dis emitted from the per-node counts.
__global__ __launch_bounds__(256)
void k_csr(const uint* __restrict__ staging, const int* __restrict__ bbase,
           ushort* __restrict__ csr, int* __restrict__ row_ptr,
           float* __restrict__ dis, int n) {
  __shared__ uint ent[CSRMAX];
  __shared__ ushort srt[CSRMAX];
  __shared__ int cnt_[256], ofs_[256], cur_[256];
  int b = blockIdx.x, t = threadIdx.x;
  int base = bbase[b];
  int cnt = bbase[b + 1] - base;
  if (cnt > CSRMAX) cnt = CSRMAX;  // statistically unreachable
  for (int i = t; i < cnt; i += 256) ent[i] = staging[base + i];
  cnt_[t] = 0;
  __syncthreads();
  for (int i = t; i < cnt; i += 256) atomicAdd(&cnt_[(ent[i] >> 16) & 255], 1);
  __syncthreads();
  ofs_[t] = cnt_[t];
  __syncthreads();
#pragma unroll
  for (int off = 1; off < 256; off <<= 1) {
    int y = (t >= off) ? ofs_[t - off] : 0;
    __syncthreads();
    ofs_[t] += y;
    __syncthreads();
  }
  int myofs = ofs_[t] - cnt_[t];  // exclusive within bucket
  ofs_[t] = myofs;
  cur_[t] = 0;
  __syncthreads();
  int node = (b << 8) + t;
  if (node < n) {
    row_ptr[node] = base + myofs;
    dis[node] = rsqrtf((float)(cnt_[t] + 1));
  }
  for (int i = t; i < cnt; i += 256) {
    uint e = ent[i];
    int dl = (e >> 16) & 255;
    int p = ofs_[dl] + atomicAdd(&cur_[dl], 1);
    srt[p] = (ushort)(e & 0xffff);
  }
  __syncthreads();
  for (int i = t; i < cnt; i += 256) csr[base + i] = srt[i];
}

// ---------------- weight prep: Wt[n][k] bf16 for W1,W2,W3 + fcW (pad 40->48) ----
__global__ void k_prepw(const float* __restrict__ W1, const float* __restrict__ W2,
                        const float* __restrict__ W3, const float* __restrict__ fcW,
                        ushort* __restrict__ wt) {
  int idx = blockIdx.x * 256 + threadIdx.x;
  if (idx < 49152) {
    int r = idx >> 14;
    int i = idx & 16383;
    int nn = i >> 7, k = i & 127;
    const float* W = (r == 0) ? W1 : ((r == 1) ? W2 : W3);
    wt[idx] = bf1(W[k * 128 + nn]);
  } else if (idx < 55296) {
    int i = idx - 49152;
    int nn = i >> 7, k = i & 127;
    wt[idx] = (nn < NC) ? bf1(fcW[k * NC + nn]) : (ushort)0;
  }
}

// ---------------- MFMA GEMM: C_bf16[n,128] = relu(bn(A)) @ W ----------------
template<int BF16IN>
__global__ __launch_bounds__(256)
void k_gemm_mx(const void* __restrict__ Ain, const uint* __restrict__ Wt,
               ushort* __restrict__ Cb, int n,
               const float* __restrict__ scale, const float* __restrict__ shift) {
  const int lane = threadIdx.x & 63;
  const int wave = threadIdx.x >> 6;
  const int quad = lane >> 4;
  const int ml = lane & 15;
  const int row0 = blockIdx.x * 64 + wave * 16;
  const int arow = row0 + ml;
  ffrag acc[8];
#pragma unroll
  for (int i = 0; i < 8; ++i) acc[i] = (ffrag){0.f, 0.f, 0.f, 0.f};

#pragma unroll
  for (int s = 0; s < 4; ++s) {
    const int k0 = s * 32 + quad * 8;
    FragU a;
    if (arow < n) {
      if (BF16IN) {
        const uint* Ab = (const uint*)Ain;
        uint4 v = *(const uint4*)&Ab[(size_t)arow * 64 + (k0 >> 1)];
        float4 sc0 = *(const float4*)&scale[k0];
        float4 sc1 = *(const float4*)&scale[k0 + 4];
        float4 sh0 = *(const float4*)&shift[k0];
        float4 sh1 = *(const float4*)&shift[k0 + 4];
        a.u.x = bf2(fmaxf(fmaf(ulo(v.x), sc0.x, sh0.x), 0.f), fmaxf(fmaf(uhi(v.x), sc0.y, sh0.y), 0.f));
        a.u.y = bf2(fmaxf(fmaf(ulo(v.y), sc0.z, sh0.z), 0.f), fmaxf(fmaf(uhi(v.y), sc0.w, sh0.w), 0.f));
        a.u.z = bf2(fmaxf(fmaf(ulo(v.z), sc1.x, sh1.x), 0.f), fmaxf(fmaf(uhi(v.z), sc1.y, sh1.y), 0.f));
        a.u.w = bf2(fmaxf(fmaf(ulo(v.w), sc1.z, sh1.z), 0.f), fmaxf(fmaf(uhi(v.w), sc1.w, sh1.w), 0.f));
      } else {
        const float* Af = (const float*)Ain;
        float4 a0 = *(const float4*)&Af[(size_t)arow * 128 + k0];
        float4 a1 = *(const float4*)&Af[(size_t)arow * 128 + k0 + 4];
        a.u.x = bf2(a0.x, a0.y);
        a.u.y = bf2(a0.z, a0.w);
        a.u.z = bf2(a1.x, a1.y);
        a.u.w = bf2(a1.z, a1.w);
      }
    } else {
      a.u = make_uint4(0, 0, 0, 0);
    }
#pragma unroll
    for (int nt = 0; nt < 8; ++nt) {
      FragU b;
      b.u = *(const uint4*)&Wt[(size_t)(nt * 16 + ml) * 64 + (k0 >> 1)];
      acc[nt] = __builtin_amdgcn_mfma_f32_16x16x32_bf16(a.f, b.f, acc[nt], 0, 0, 0);
    }
  }
#pragma unroll
  for (int nt = 0; nt < 8; ++nt) {
#pragma unroll
    for (int r = 0; r < 4; ++r) {
      int orow = row0 + quad * 4 + r;
      if (orow < n) Cb[(size_t)orow * 128 + nt * 16 + ml] = bf1(acc[nt][r]);
    }
  }
}

// ---------------- aggregation: hb[d] = bf16( dis[d]^2*t[d] + sum_e w_e * t[src_e] ) ----
__global__ __launch_bounds__(256)
void k_agg(const uint* __restrict__ t, const int* __restrict__ row_ptr,
           const ushort* __restrict__ csr, const float* __restrict__ dis,
           uint* __restrict__ hb, int n) {
  int node = (blockIdx.x * 256 + threadIdx.x) >> 6;
  if (node >= n) return;
  int lane = threadIdx.x & 63;
  int quarter = lane >> 4;       // which of 4 concurrent edges
  int fl = lane & 15;            // 16B segment within the 256B row
  int e0 = row_ptr[node], e1 = row_ptr[node + 1];
  float dd = dis[node];
  float acc[8] = {};

  for (int chunk = e0; chunk < e1; chunk += 64) {
    int m = min(64, e1 - chunk);
    int s = 0;
    float w = 0.f;
    if (lane < m) {
      s = csr[chunk + lane];
      w = dis[s] * dd;
    }
#pragma unroll 4
    for (int j = 0; j < m; j += 4) {
      int jj = j + quarter;
      int ss = __shfl(s, jj, 64);
      float ww = __shfl(w, jj, 64);
      if (jj < m) {
        uint4 v = *(const uint4*)&t[(size_t)ss * 64 + (fl << 2)];
        acc[0] = fmaf(ww, ulo(v.x), acc[0]);
        acc[1] = fmaf(ww, uhi(v.x), acc[1]);
        acc[2] = fmaf(ww, ulo(v.y), acc[2]);
        acc[3] = fmaf(ww, uhi(v.y), acc[3]);
        acc[4] = fmaf(ww, ulo(v.z), acc[4]);
        acc[5] = fmaf(ww, uhi(v.z), acc[5]);
        acc[6] = fmaf(ww, ulo(v.w), acc[6]);
        acc[7] = fmaf(ww, uhi(v.w), acc[7]);
      }
    }
  }
#pragma unroll
  for (int j = 0; j < 8; ++j) {
    acc[j] += __shfl_xor(acc[j], 16, 64);
    acc[j] += __shfl_xor(acc[j], 32, 64);
  }
  if (quarter == 0) {
    float d2 = dd * dd;
    uint4 v = *(const uint4*)&t[(size_t)node * 64 + (fl << 2)];
    acc[0] = fmaf(d2, ulo(v.x), acc[0]);
    acc[1] = fmaf(d2, uhi(v.x), acc[1]);
    acc[2] = fmaf(d2, ulo(v.y), acc[2]);
    acc[3] = fmaf(d2, uhi(v.y), acc[3]);
    acc[4] = fmaf(d2, ulo(v.z), acc[4]);
    acc[5] = fmaf(d2, uhi(v.z), acc[5]);
    acc[6] = fmaf(d2, ulo(v.w), acc[6]);
    acc[7] = fmaf(d2, uhi(v.w), acc[7]);
    uint4 o;
    o.x = bf2(acc[0], acc[1]);
    o.y = bf2(acc[2], acc[3]);
    o.z = bf2(acc[4], acc[5]);
    o.w = bf2(acc[6], acc[7]);
    *(uint4*)&hb[(size_t)node * 64 + (fl << 2)] = o;
  }
}

// ---------------- BN stats over bf16 hb: stats[f]=sum, stats[128+f]=sumsq ----
__global__ __launch_bounds__(256)
void k_stats(const uint* __restrict__ hb, float* __restrict__ stats, int n, int rpb) {
  int f2 = threadIdx.x & 63;   // feature pair
  int q  = threadIdx.x >> 6;   // 0..3 row phase
  int r0 = blockIdx.x * rpb, r1 = min(n, r0 + rpb);
  float sa = 0.f, qa = 0.f, sb = 0.f, qb = 0.f;
  for (int r = r0 + q; r < r1; r += 4) {
    uint u = hb[(size_t)r * 64 + f2];
    float a = ulo(u), b = uhi(u);
    sa += a; qa += a * a; sb += b; qb += b * b;
  }
  __shared__ float4 red[256];
  red[threadIdx.x] = make_float4(sa, qa, sb, qb);
  __syncthreads();
  if (q == 0) {
    float4 v0 = red[f2], v1 = red[64 + f2], v2 = red[128 + f2], v3 = red[192 + f2];
    atomicAdd(&stats[2 * f2],       v0.x + v1.x + v2.x + v3.x);
    atomicAdd(&stats[2 * f2 + 1],   v0.z + v1.z + v2.z + v3.z);
    atomicAdd(&stats[128 + 2 * f2], v0.y + v1.y + v2.y + v3.y);
    atomicAdd(&stats[129 + 2 * f2], v0.w + v1.w + v2.w + v3.w);
  }
}

// ---------------- BN params: scale = g*rstd, shift = be - m*scale ----------------
__global__ void k_bnparams(const float* __restrict__ stats, const float* __restrict__ g,
                           const float* __restrict__ be, float* __restrict__ scale,
                           float* __restrict__ shift, int n) {
  int f = threadIdx.x;  // 128
  float inv_n = 1.0f / (float)n;
  float m = stats[f] * inv_n;
  float var = stats[128 + f] * inv_n - m * m;
  float rstd = rsqrtf(var + EPSV);
  float sc = g[f] * rstd;
  scale[f] = sc;
  shift[f] = be[f] - m * sc;
}

// ---------------- MFMA FC + ReLU + log_softmax ----------------
__global__ __launch_bounds__(256)
void k_fc_mx(const uint* __restrict__ hb, const float* __restrict__ scale,
             const float* __restrict__ shift, const uint* __restrict__ fWt,
             const float* __restrict__ fcb, float* __restrict__ out, int n) {
  const int lane = threadIdx.x & 63;
  const int wave = threadIdx.x >> 6;
  const int quad = lane >> 4;
  const int ml = lane & 15;
  const int row0 = blockIdx.x * 64 + wave * 16;
  const int arow = row0 + ml;
  ffrag acc[3];
#pragma unroll
  for (int i = 0; i < 3; ++i) acc[i] = (ffrag){0.f, 0.f, 0.f, 0.f};

#pragma unroll
  for (int s = 0; s < 4; ++s) {
    const int k0 = s * 32 + quad * 8;
    FragU a;
    if (arow < n) {
      uint4 v = *(const uint4*)&hb[(size_t)arow * 64 + (k0 >> 1)];
      float4 sc0 = *(const float4*)&scale[k0];
      float4 sc1 = *(const float4*)&scale[k0 + 4];
      float4 sh0 = *(const float4*)&shift[k0];
      float4 sh1 = *(const float4*)&shift[k0 + 4];
      a.u.x = bf2(fmaxf(fmaf(ulo(v.x), sc0.x, sh0.x), 0.f), fmaxf(fmaf(uhi(v.x), sc0.y, sh0.y), 0.f));
      a.u.y = bf2(fmaxf(fmaf(ulo(v.y), sc0.z, sh0.z), 0.f), fmaxf(fmaf(uhi(v.y), sc0.w, sh0.w), 0.f));
      a.u.z = bf2(fmaxf(fmaf(ulo(v.z), sc1.x, sh1.x), 0.f), fmaxf(fmaf(uhi(v.z), sc1.y, sh1.y), 0.f));
      a.u.w = bf2(fmaxf(fmaf(ulo(v.w), sc1.z, sh1.z), 0.f), fmaxf(fmaf(uhi(v.w), sc1.w, sh1.w), 0.f));
    } else {
      a.u = make_uint4(0, 0, 0, 0);
    }
#pragma unroll
    for (int nt = 0; nt < 3; ++nt) {
      FragU b;
      b.u = *(const uint4*)&fWt[(size_t)(nt * 16 + ml) * 64 + (k0 >> 1)];
      acc[nt] = __builtin_amdgcn_mfma_f32_16x16x32_bf16(a.f, b.f, acc[nt], 0, 0, 0);
    }
  }

  float b0 = fcb[ml], b1 = fcb[16 + ml];
  float b2 = (ml < 8) ? fcb[32 + ml] : 0.f;
#pragma unroll
  for (int r = 0; r < 4; ++r) {
    int orow = row0 + quad * 4 + r;
    if (orow >= n) continue;
    float l0 = fmaxf(acc[0][r] + b0, 0.f);
    float l1 = fmaxf(acc[1][r] + b1, 0.f);
    float l2 = (ml < 8) ? fmaxf(acc[2][r] + b2, 0.f) : -1e30f;
    float mx = fmaxf(fmaxf(l0, l1), l2);
#pragma unroll
    for (int off = 1; off < 16; off <<= 1) mx = fmaxf(mx, __shfl_xor(mx, off, 64));
    float sm = __expf(l0 - mx) + __expf(l1 - mx) + ((ml < 8) ? __expf(l2 - mx) : 0.f);
#pragma unroll
    for (int off = 1; off < 16; off <<= 1) sm += __shfl_xor(sm, off, 64);
    float lse = mx + __logf(sm);
    float* o1 = out + (size_t)orow * NC;
    float* o2 = out + (size_t)NODES * NC + (size_t)orow * NC;
    o1[ml] = l0 - lse;
    o1[16 + ml] = l1 - lse;
    o2[ml] = l0;
    o2[16 + ml] = l1;
    if (ml < 8) {
      o1[32 + ml] = l2 - lse;
      o2[32 + ml] = l2;
    }
  }
}

// ---------------- launch ----------------

extern "C" void kernel_launch(void* const* d_in, const int* in_sizes, int n_in,
                              void* d_out, int out_size, void* d_ws, size_t ws_size,
                              hipStream_t stream) {
  (void)in_sizes; (void)n_in; (void)out_size; (void)ws_size;
  const float* x   = (const float*)d_in[0];
  const int*   ei  = (const int*)d_in[1];
  const float* W1  = (const float*)d_in[2];
  const float* W2  = (const float*)d_in[4];
  const float* W3  = (const float*)d_in[6];
  const float* g1  = (const float*)d_in[8];
  const float* be1 = (const float*)d_in[9];
  const float* g2  = (const float*)d_in[10];
  const float* be2 = (const float*)d_in[11];
  const float* g3  = (const float*)d_in[12];
  const float* be3 = (const float*)d_in[13];
  const float* fcW = (const float*)d_in[14];
  const float* fcb = (const float*)d_in[15];
  float* out = (float*)d_out;

  const int n = NODES, e_ = EDGES;
  const int* srcp = ei;        // edge_index[0]
  const int* dstp = ei + e_;   // edge_index[1]

  char* ws = (char*)d_ws;
  size_t off = 0;
  auto alloc = [&](size_t bytes) {
    char* p = ws + off;
    off = (off + bytes + 255) & ~(size_t)255;
    return p;
  };
  float* dis    = (float*)alloc((size_t)n * 4);
  int*   bcnt   = (int*)  alloc(256 * 4);
  int*   bbase  = (int*)  alloc(257 * 4);
  int*   bcur   = (int*)  alloc(256 * 4);
  int*   row_ptr= (int*)  alloc((size_t)(n + 1) * 4);
  uint*  staging= (uint*) alloc((size_t)e_ * 4);
  ushort* csr   = (ushort*)alloc((size_t)e_ * 2);
  uint*  tbuf   = (uint*) alloc((size_t)n * 64 * 4);   // bf16-packed [n,128]
  uint*  hbuf   = (uint*) alloc((size_t)n * 64 * 4);   // bf16-packed [n,128]
  ushort* wbuf  = (ushort*)alloc(55296 * 2);           // Wt1,Wt2,Wt3,fcWt
  float* stats  = (float*)alloc(256 * 4);
  float* scale  = (float*)alloc(128 * 4);
  float* shift  = (float*)alloc(128 * 4);

  const uint* Wt1  = (const uint*)wbuf;
  const uint* Wt2  = (const uint*)wbuf + 8192;
  const uint* Wt3  = (const uint*)wbuf + 16384;
  const uint* fWt  = (const uint*)wbuf + 24576;

  const int ebk = (e_ + 8191) / 8192;   // 196 edge chunks

  hipMemsetAsync(bcnt, 0, 256 * 4, stream);
  k_bcount<<<ebk, 256, 0, stream>>>(dstp, bcnt, e_);
  k_bscan<<<1, 256, 0, stream>>>(bcnt, bbase, bcur, row_ptr);
  k_bin<<<ebk, 256, 0, stream>>>(srcp, dstp, bcur, staging, e_);
  k_csr<<<NBKT, 256, 0, stream>>>(staging, bbase, csr, row_ptr, dis, n);
  k_prepw<<<216, 256, 0, stream>>>(W1, W2, W3, fcW, wbuf);

  const int ggrid = (n + 63) / 64;      // 782
  const int srpb  = (n + 127) / 128;    // 391
  const uint* Wts[3] = {Wt1, Wt2, Wt3};
  const float* gl[3]  = {g1, g2, g3};
  const float* bel[3] = {be1, be2, be3};

  for (int L = 0; L < 3; ++L) {
    if (L == 0)
      k_gemm_mx<0><<<ggrid, 256, 0, stream>>>(x, Wts[L], (ushort*)tbuf, n, nullptr, nullptr);
    else
      k_gemm_mx<1><<<ggrid, 256, 0, stream>>>(hbuf, Wts[L], (ushort*)tbuf, n, scale, shift);
    k_agg<<<(n + 3) / 4, 256, 0, stream>>>(tbuf, row_ptr, csr, dis, hbuf, n);
    hipMemsetAsync(stats, 0, 256 * 4, stream);
    k_stats<<<128, 256, 0, stream>>>(hbuf, stats, n, srpb);
    k_bnparams<<<1, 128, 0, stream>>>(stats, gl[L], bel[L], scale, shift, n);
  }
  k_fc_mx<<<ggrid, 256, 0, stream>>>(hbuf, scale, shift, fWt, fcb, out, n);
}

// Round 6
// 397.624 us; speedup vs baseline: 2.8634x; 1.2310x over previous
//
#include <hip/hip_runtime.h>
#include <hip/hip_bf16.h>
#include <math.h>

#define NODES 50000
#define EDGES 1600000
#define HD    128
#define NC    40
#define EPSV  1e-5f
#define NBKT  196           // ceil(50000/256)
#define CSRMAX 12032        // per-bucket staging cap (mean 8192)

typedef unsigned int uint;
typedef unsigned short ushort;
typedef __attribute__((ext_vector_type(8))) short bfrag;
typedef __attribute__((ext_vector_type(4))) float ffrag;

union FragU { uint4 u; bfrag f; };

__device__ inline ushort bf1(float x) {
  uint u = __float_as_uint(x);
  return (ushort)((u + 0x7fffu + ((u >> 16) & 1u)) >> 16);
}
__device__ inline uint bf2(float a, float b) {
  return (uint)bf1(a) | ((uint)bf1(b) << 16);
}
__device__ inline float ulo(uint u) { return __uint_as_float(u << 16); }
__device__ inline float uhi(uint u) { return __uint_as_float(u & 0xffff0000u); }

// ---------------- graph build: bucket-binned, coalesced-write CSR ----------------

__global__ __launch_bounds__(256)
void k_bcount(const int* __restrict__ dst, int* __restrict__ bcnt, int e_) {
  __shared__ int h[256];
  int t = threadIdx.x;
  h[t] = 0;
  __syncthreads();
  int base = blockIdx.x * 8192;
  int cntE = min(8192, e_ - base);
  for (int i = t; i < cntE; i += 256) atomicAdd(&h[dst[base + i] >> 8], 1);
  __syncthreads();
  if (h[t]) atomicAdd(&bcnt[t], h[t]);
}

__global__ void k_bscan(const int* __restrict__ bcnt, int* __restrict__ bbase,
                        int* __restrict__ bcur, int* __restrict__ row_ptr) {
  __shared__ int s[256];
  int t = threadIdx.x;
  int v = bcnt[t];
  s[t] = v;
  __syncthreads();
#pragma unroll
  for (int off = 1; off < 256; off <<= 1) {
    int y = (t >= off) ? s[t - off] : 0;
    __syncthreads();
    s[t] += y;
    __syncthreads();
  }
  int excl = s[t] - v;
  bbase[t] = excl;
  bcur[t] = excl;
  if (t == 255) {
    bbase[256] = s[255];
    row_ptr[NODES] = s[255];
  }
}

// staged entry: src(0:15) | dstLow(16:23) | bucket(24:31)
__global__ __launch_bounds__(256)
void k_bin(const int* __restrict__ src, const int* __restrict__ dst,
           int* __restrict__ bcur, uint* __restrict__ staging, int e_) {
  __shared__ uint ent[8192];
  __shared__ int h[256], inc[256], lofs[256], cur[256], gb[256];
  int t = threadIdx.x;
  h[t] = 0;
  __syncthreads();
  int base = blockIdx.x * 8192;
  int cntE = min(8192, e_ - base);
  for (int i = t; i < cntE; i += 256) atomicAdd(&h[dst[base + i] >> 8], 1);
  __syncthreads();
  inc[t] = h[t];
  __syncthreads();
#pragma unroll
  for (int off = 1; off < 256; off <<= 1) {
    int y = (t >= off) ? inc[t - off] : 0;
    __syncthreads();
    inc[t] += y;
    __syncthreads();
  }
  lofs[t] = inc[t] - h[t];
  cur[t] = 0;
  __syncthreads();
  for (int i = t; i < cntE; i += 256) {
    int e = base + i;
    int d = dst[e];
    int b = d >> 8;
    uint en = (uint)(src[e] & 0xffff) | ((uint)(d & 255) << 16) | ((uint)b << 24);
    int p = lofs[b] + atomicAdd(&cur[b], 1);
    ent[p] = en;
  }
  __syncthreads();
  if (h[t]) gb[t] = atomicAdd(&bcur[t], h[t]);
  __syncthreads();
  for (int i = t; i < cntE; i += 256) {
    uint en = ent[i];
    int b = en >> 24;
    staging[gb[b] + (i - lofs[b])] = en;
  }
}

__global__ __launch_bounds__(256)
void k_csr(const uint* __restrict__ staging, const int* __restrict__ bbase,
           ushort* __restrict__ csr, int* __restrict__ row_ptr,
           float* __restrict__ dis, int n) {
  __shared__ uint ent[CSRMAX];
  __shared__ ushort srt[CSRMAX];
  __shared__ int cnt_[256], ofs_[256], cur_[256];
  int b = blockIdx.x, t = threadIdx.x;
  int base = bbase[b];
  int cnt = bbase[b + 1] - base;
  if (cnt > CSRMAX) cnt = CSRMAX;  // statistically unreachable
  for (int i = t; i < cnt; i += 256) ent[i] = staging[base + i];
  cnt_[t] = 0;
  __syncthreads();
  for (int i = t; i < cnt; i += 256) atomicAdd(&cnt_[(ent[i] >> 16) & 255], 1);
  __syncthreads();
  ofs_[t] = cnt_[t];
  __syncthreads();
#pragma unroll
  for (int off = 1; off < 256; off <<= 1) {
    int y = (t >= off) ? ofs_[t - off] : 0;
    __syncthreads();
    ofs_[t] += y;
    __syncthreads();
  }
  int myofs = ofs_[t] - cnt_[t];
  ofs_[t] = myofs;
  cur_[t] = 0;
  __syncthreads();
  int node = (b << 8) + t;
  if (node < n) {
    row_ptr[node] = base + myofs;
    dis[node] = rsqrtf((float)(cnt_[t] + 1));
  }
  for (int i = t; i < cnt; i += 256) {
    uint e = ent[i];
    int dl = (e >> 16) & 255;
    int p = ofs_[dl] + atomicAdd(&cur_[dl], 1);
    srt[p] = (ushort)(e & 0xffff);
  }
  __syncthreads();
  for (int i = t; i < cnt; i += 256) csr[base + i] = srt[i];
}

// ---------------- weight prep ----------------
__global__ void k_prepw(const float* __restrict__ W1, const float* __restrict__ W2,
                        const float* __restrict__ W3, const float* __restrict__ fcW,
                        ushort* __restrict__ wt) {
  int idx = blockIdx.x * 256 + threadIdx.x;
  if (idx < 49152) {
    int r = idx >> 14;
    int i = idx & 16383;
    int nn = i >> 7, k = i & 127;
    const float* W = (r == 0) ? W1 : ((r == 1) ? W2 : W3);
    wt[idx] = bf1(W[k * 128 + nn]);
  } else if (idx < 55296) {
    int i = idx - 49152;
    int nn = i >> 7, k = i & 127;
    wt[idx] = (nn < NC) ? bf1(fcW[k * NC + nn]) : (ushort)0;
  }
}

// ---------------- stats->scale/shift prologue (shared by gemm/fc) ----------------
// part[p][t]: p in [0,64), t<128 = sum_f, t>=128 = sumsq_f
__device__ inline void bn_prologue(const float* __restrict__ part,
                                   const float* __restrict__ g,
                                   const float* __restrict__ be,
                                   float* s_scale, float* s_shift) {
  __shared__ float tmp[256];
  int t = threadIdx.x;
  float s = 0.f;
#pragma unroll 8
  for (int p = 0; p < 64; ++p) s += part[p * 256 + t];
  tmp[t] = s;
  __syncthreads();
  if (t < 128) {
    const float inv_n = 1.0f / (float)NODES;
    float m = tmp[t] * inv_n;
    float var = tmp[128 + t] * inv_n - m * m;
    float rstd = rsqrtf(var + EPSV);
    float sc = g[t] * rstd;
    s_scale[t] = sc;
    s_shift[t] = be[t] - m * sc;
  }
  __syncthreads();
}

// ---------------- MFMA GEMM: C_bf16[n,128] = relu(bn(A)) @ W ----------------
// MODE 0: A fp32, no BN (layer 1). MODE 1: A packed bf16 + BN(from parts) + relu.
template<int MODE>
__global__ __launch_bounds__(256)
void k_gemm_mx(const void* __restrict__ Ain, const uint* __restrict__ Wt,
               ushort* __restrict__ Cb, int n,
               const float* __restrict__ part, const float* __restrict__ g,
               const float* __restrict__ be) {
  __shared__ float s_scale[128], s_shift[128];
  if (MODE == 1) bn_prologue(part, g, be, s_scale, s_shift);

  const int lane = threadIdx.x & 63;
  const int wave = threadIdx.x >> 6;
  const int quad = lane >> 4;
  const int ml = lane & 15;
  const int row0 = blockIdx.x * 64 + wave * 16;
  const int arow = row0 + ml;
  ffrag acc[8];
#pragma unroll
  for (int i = 0; i < 8; ++i) acc[i] = (ffrag){0.f, 0.f, 0.f, 0.f};

#pragma unroll
  for (int s = 0; s < 4; ++s) {
    const int k0 = s * 32 + quad * 8;
    FragU a;
    if (arow < n) {
      if (MODE == 1) {
        const uint* Ab = (const uint*)Ain;
        uint4 v = *(const uint4*)&Ab[(size_t)arow * 64 + (k0 >> 1)];
        float4 sc0 = *(const float4*)&s_scale[k0];
        float4 sc1 = *(const float4*)&s_scale[k0 + 4];
        float4 sh0 = *(const float4*)&s_shift[k0];
        float4 sh1 = *(const float4*)&s_shift[k0 + 4];
        a.u.x = bf2(fmaxf(fmaf(ulo(v.x), sc0.x, sh0.x), 0.f), fmaxf(fmaf(uhi(v.x), sc0.y, sh0.y), 0.f));
        a.u.y = bf2(fmaxf(fmaf(ulo(v.y), sc0.z, sh0.z), 0.f), fmaxf(fmaf(uhi(v.y), sc0.w, sh0.w), 0.f));
        a.u.z = bf2(fmaxf(fmaf(ulo(v.z), sc1.x, sh1.x), 0.f), fmaxf(fmaf(uhi(v.z), sc1.y, sh1.y), 0.f));
        a.u.w = bf2(fmaxf(fmaf(ulo(v.w), sc1.z, sh1.z), 0.f), fmaxf(fmaf(uhi(v.w), sc1.w, sh1.w), 0.f));
      } else {
        const float* Af = (const float*)Ain;
        float4 a0 = *(const float4*)&Af[(size_t)arow * 128 + k0];
        float4 a1 = *(const float4*)&Af[(size_t)arow * 128 + k0 + 4];
        a.u.x = bf2(a0.x, a0.y);
        a.u.y = bf2(a0.z, a0.w);
        a.u.z = bf2(a1.x, a1.y);
        a.u.w = bf2(a1.z, a1.w);
      }
    } else {
      a.u = make_uint4(0, 0, 0, 0);
    }
#pragma unroll
    for (int nt = 0; nt < 8; ++nt) {
      FragU b;
      b.u = *(const uint4*)&Wt[(size_t)(nt * 16 + ml) * 64 + (k0 >> 1)];
      acc[nt] = __builtin_amdgcn_mfma_f32_16x16x32_bf16(a.f, b.f, acc[nt], 0, 0, 0);
    }
  }
#pragma unroll
  for (int nt = 0; nt < 8; ++nt) {
#pragma unroll
    for (int r = 0; r < 4; ++r) {
      int orow = row0 + quad * 4 + r;
      if (orow < n) Cb[(size_t)orow * 128 + nt * 16 + ml] = bf1(acc[nt][r]);
    }
  }
}

// ---------------- aggregation + fused BN-stats ----------------
// hb[d] = bf16( dis[d]^2*t[d] + sum_e w_e * t[src_e] ); block also reduces
// sum/sumsq of its 4 fp32 rows into part[blockIdx&63][256].
__global__ __launch_bounds__(256)
void k_agg(const uint* __restrict__ t, const int* __restrict__ row_ptr,
           const ushort* __restrict__ csr, const float* __restrict__ dis,
           uint* __restrict__ hb, float* __restrict__ part, int n) {
  __shared__ float red[4][256];
  int node = (blockIdx.x * 256 + threadIdx.x) >> 6;
  int lane = threadIdx.x & 63;
  int wave = threadIdx.x >> 6;
  int quarter = lane >> 4;
  int fl = lane & 15;
  int e0 = row_ptr[node], e1 = row_ptr[node + 1];
  float dd = dis[node];
  float acc[8] = {};

  for (int chunk = e0; chunk < e1; chunk += 64) {
    int m = min(64, e1 - chunk);
    int s = 0;
    float w = 0.f;
    if (lane < m) {
      s = csr[chunk + lane];
      w = dis[s] * dd;
    }
    // two independent gathers in flight per iteration
#pragma unroll 2
    for (int j = 0; j < m; j += 8) {
      int j0 = j + quarter, j1 = j + 4 + quarter;
      int s0 = __shfl(s, j0, 64), s1 = __shfl(s, j1, 64);
      float w0 = __shfl(w, j0, 64), w1 = __shfl(w, j1, 64);
      bool p0 = j0 < m, p1 = j1 < m;
      uint4 v0 = make_uint4(0, 0, 0, 0), v1 = make_uint4(0, 0, 0, 0);
      if (p0) v0 = *(const uint4*)&t[(size_t)s0 * 64 + (fl << 2)];
      if (p1) v1 = *(const uint4*)&t[(size_t)s1 * 64 + (fl << 2)];
      if (p0) {
        acc[0] = fmaf(w0, ulo(v0.x), acc[0]);
        acc[1] = fmaf(w0, uhi(v0.x), acc[1]);
        acc[2] = fmaf(w0, ulo(v0.y), acc[2]);
        acc[3] = fmaf(w0, uhi(v0.y), acc[3]);
        acc[4] = fmaf(w0, ulo(v0.z), acc[4]);
        acc[5] = fmaf(w0, uhi(v0.z), acc[5]);
        acc[6] = fmaf(w0, ulo(v0.w), acc[6]);
        acc[7] = fmaf(w0, uhi(v0.w), acc[7]);
      }
      if (p1) {
        acc[0] = fmaf(w1, ulo(v1.x), acc[0]);
        acc[1] = fmaf(w1, uhi(v1.x), acc[1]);
        acc[2] = fmaf(w1, ulo(v1.y), acc[2]);
        acc[3] = fmaf(w1, uhi(v1.y), acc[3]);
        acc[4] = fmaf(w1, ulo(v1.z), acc[4]);
        acc[5] = fmaf(w1, uhi(v1.z), acc[5]);
        acc[6] = fmaf(w1, ulo(v1.w), acc[6]);
        acc[7] = fmaf(w1, uhi(v1.w), acc[7]);
      }
    }
  }
#pragma unroll
  for (int j = 0; j < 8; ++j) {
    acc[j] += __shfl_xor(acc[j], 16, 64);
    acc[j] += __shfl_xor(acc[j], 32, 64);
  }
  if (quarter == 0) {
    float d2 = dd * dd;
    uint4 v = *(const uint4*)&t[(size_t)node * 64 + (fl << 2)];
    acc[0] = fmaf(d2, ulo(v.x), acc[0]);
    acc[1] = fmaf(d2, uhi(v.x), acc[1]);
    acc[2] = fmaf(d2, ulo(v.y), acc[2]);
    acc[3] = fmaf(d2, uhi(v.y), acc[3]);
    acc[4] = fmaf(d2, ulo(v.z), acc[4]);
    acc[5] = fmaf(d2, uhi(v.z), acc[5]);
    acc[6] = fmaf(d2, ulo(v.w), acc[6]);
    acc[7] = fmaf(d2, uhi(v.w), acc[7]);
    uint4 o;
    o.x = bf2(acc[0], acc[1]);
    o.y = bf2(acc[2], acc[3]);
    o.z = bf2(acc[4], acc[5]);
    o.w = bf2(acc[6], acc[7]);
    *(uint4*)&hb[(size_t)node * 64 + (fl << 2)] = o;
    // stats contribution: features fl*8 .. fl*8+7
    *(float4*)&red[wave][fl * 8]     = make_float4(acc[0], acc[1], acc[2], acc[3]);
    *(float4*)&red[wave][fl * 8 + 4] = make_float4(acc[4], acc[5], acc[6], acc[7]);
  }
  __syncthreads();
  int tt = threadIdx.x;
  if (tt < 128) {
    float s = red[0][tt] + red[1][tt] + red[2][tt] + red[3][tt];
    atomicAdd(&part[(blockIdx.x & 63) * 256 + tt], s);
  } else {
    int f = tt - 128;
    float s = red[0][f] * red[0][f] + red[1][f] * red[1][f] +
              red[2][f] * red[2][f] + red[3][f] * red[3][f];
    atomicAdd(&part[(blockIdx.x & 63) * 256 + tt], s);
  }
}

// ---------------- MFMA FC + BN prologue + ReLU + log_softmax ----------------
__global__ __launch_bounds__(256)
void k_fc_mx(const uint* __restrict__ hb, const float* __restrict__ part,
             const float* __restrict__ g, const float* __restrict__ be,
             const uint* __restrict__ fWt, const float* __restrict__ fcb,
             float* __restrict__ out, int n) {
  __shared__ float s_scale[128], s_shift[128];
  bn_prologue(part, g, be, s_scale, s_shift);

  const int lane = threadIdx.x & 63;
  const int wave = threadIdx.x >> 6;
  const int quad = lane >> 4;
  const int ml = lane & 15;
  const int row0 = blockIdx.x * 64 + wave * 16;
  const int arow = row0 + ml;
  ffrag acc[3];
#pragma unroll
  for (int i = 0; i < 3; ++i) acc[i] = (ffrag){0.f, 0.f, 0.f, 0.f};

#pragma unroll
  for (int s = 0; s < 4; ++s) {
    const int k0 = s * 32 + quad * 8;
    FragU a;
    if (arow < n) {
      uint4 v = *(const uint4*)&hb[(size_t)arow * 64 + (k0 >> 1)];
      float4 sc0 = *(const float4*)&s_scale[k0];
      float4 sc1 = *(const float4*)&s_scale[k0 + 4];
      float4 sh0 = *(const float4*)&s_shift[k0];
      float4 sh1 = *(const float4*)&s_shift[k0 + 4];
      a.u.x = bf2(fmaxf(fmaf(ulo(v.x), sc0.x, sh0.x), 0.f), fmaxf(fmaf(uhi(v.x), sc0.y, sh0.y), 0.f));
      a.u.y = bf2(fmaxf(fmaf(ulo(v.y), sc0.z, sh0.z), 0.f), fmaxf(fmaf(uhi(v.y), sc0.w, sh0.w), 0.f));
      a.u.z = bf2(fmaxf(fmaf(ulo(v.z), sc1.x, sh1.x), 0.f), fmaxf(fmaf(uhi(v.z), sc1.y, sh1.y), 0.f));
      a.u.w = bf2(fmaxf(fmaf(ulo(v.w), sc1.z, sh1.z), 0.f), fmaxf(fmaf(uhi(v.w), sc1.w, sh1.w), 0.f));
    } else {
      a.u = make_uint4(0, 0, 0, 0);
    }
#pragma unroll
    for (int nt = 0; nt < 3; ++nt) {
      FragU b;
      b.u = *(const uint4*)&fWt[(size_t)(nt * 16 + ml) * 64 + (k0 >> 1)];
      acc[nt] = __builtin_amdgcn_mfma_f32_16x16x32_bf16(a.f, b.f, acc[nt], 0, 0, 0);
    }
  }

  float b0 = fcb[ml], b1 = fcb[16 + ml];
  float b2 = (ml < 8) ? fcb[32 + ml] : 0.f;
#pragma unroll
  for (int r = 0; r < 4; ++r) {
    int orow = row0 + quad * 4 + r;
    if (orow >= n) continue;
    float l0 = fmaxf(acc[0][r] + b0, 0.f);
    float l1 = fmaxf(acc[1][r] + b1, 0.f);
    float l2 = (ml < 8) ? fmaxf(acc[2][r] + b2, 0.f) : -1e30f;
    float mx = fmaxf(fmaxf(l0, l1), l2);
#pragma unroll
    for (int off = 1; off < 16; off <<= 1) mx = fmaxf(mx, __shfl_xor(mx, off, 64));
    float sm = __expf(l0 - mx) + __expf(l1 - mx) + ((ml < 8) ? __expf(l2 - mx) : 0.f);
#pragma unroll
    for (int off = 1; off < 16; off <<= 1) sm += __shfl_xor(sm, off, 64);
    float lse = mx + __logf(sm);
    float* o1 = out + (size_t)orow * NC;
    float* o2 = out + (size_t)NODES * NC + (size_t)orow * NC;
    o1[ml] = l0 - lse;
    o1[16 + ml] = l1 - lse;
    o2[ml] = l0;
    o2[16 + ml] = l1;
    if (ml < 8) {
      o1[32 + ml] = l2 - lse;
      o2[32 + ml] = l2;
    }
  }
}

// ---------------- launch ----------------

extern "C" void kernel_launch(void* const* d_in, const int* in_sizes, int n_in,
                              void* d_out, int out_size, void* d_ws, size_t ws_size,
                              hipStream_t stream) {
  (void)in_sizes; (void)n_in; (void)out_size; (void)ws_size;
  const float* x   = (const float*)d_in[0];
  const int*   ei  = (const int*)d_in[1];
  const float* W1  = (const float*)d_in[2];
  const float* W2  = (const float*)d_in[4];
  const float* W3  = (const float*)d_in[6];
  const float* g1  = (const float*)d_in[8];
  const float* be1 = (const float*)d_in[9];
  const float* g2  = (const float*)d_in[10];
  const float* be2 = (const float*)d_in[11];
  const float* g3  = (const float*)d_in[12];
  const float* be3 = (const float*)d_in[13];
  const float* fcW = (const float*)d_in[14];
  const float* fcb = (const float*)d_in[15];
  float* out = (float*)d_out;

  const int n = NODES, e_ = EDGES;
  const int* srcp = ei;        // edge_index[0]
  const int* dstp = ei + e_;   // edge_index[1]

  char* ws = (char*)d_ws;
  size_t off = 0;
  auto alloc = [&](size_t bytes) {
    char* p = ws + off;
    off = (off + bytes + 255) & ~(size_t)255;
    return p;
  };
  float* dis    = (float*)alloc((size_t)n * 4);
  int*   bcnt   = (int*)  alloc(256 * 4);               // contiguous with parts:
  float* parts  = (float*)alloc(3 * 64 * 256 * 4);      // one memset covers both
  int*   bbase  = (int*)  alloc(257 * 4);
  int*   bcur   = (int*)  alloc(256 * 4);
  int*   row_ptr= (int*)  alloc((size_t)(n + 1) * 4);
  uint*  staging= (uint*) alloc((size_t)e_ * 4);
  ushort* csr   = (ushort*)alloc((size_t)e_ * 2);
  uint*  tbuf   = (uint*) alloc((size_t)n * 64 * 4);    // bf16-packed [n,128]
  uint*  hbuf   = (uint*) alloc((size_t)n * 64 * 4);    // bf16-packed [n,128]
  ushort* wbuf  = (ushort*)alloc(55296 * 2);            // Wt1,Wt2,Wt3,fcWt

  const uint* Wt1  = (const uint*)wbuf;
  const uint* Wt2  = (const uint*)wbuf + 8192;
  const uint* Wt3  = (const uint*)wbuf + 16384;
  const uint* fWt  = (const uint*)wbuf + 24576;

  const int ebk = (e_ + 8191) / 8192;   // 196 edge chunks

  // one memset: bcnt (1 KB) + parts (192 KB), laid out contiguously
  hipMemsetAsync(bcnt, 0, 256 * 4 + 3 * 64 * 256 * 4, stream);
  k_bcount<<<ebk, 256, 0, stream>>>(dstp, bcnt, e_);
  k_bscan<<<1, 256, 0, stream>>>(bcnt, bbase, bcur, row_ptr);
  k_bin<<<ebk, 256, 0, stream>>>(srcp, dstp, bcur, staging, e_);
  k_csr<<<NBKT, 256, 0, stream>>>(staging, bbase, csr, row_ptr, dis, n);
  k_prepw<<<216, 256, 0, stream>>>(W1, W2, W3, fcW, wbuf);

  const int ggrid = (n + 63) / 64;      // 782
  float* p0 = parts;
  float* p1 = parts + 64 * 256;
  float* p2 = parts + 2 * 64 * 256;

  k_gemm_mx<0><<<ggrid, 256, 0, stream>>>(x, Wt1, (ushort*)tbuf, n, nullptr, nullptr, nullptr);
  k_agg<<<n / 4, 256, 0, stream>>>(tbuf, row_ptr, csr, dis, hbuf, p0, n);
  k_gemm_mx<1><<<ggrid, 256, 0, stream>>>(hbuf, Wt2, (ushort*)tbuf, n, p0, g1, be1);
  k_agg<<<n / 4, 256, 0, stream>>>(tbuf, row_ptr, csr, dis, hbuf, p1, n);
  k_gemm_mx<1><<<ggrid, 256, 0, stream>>>(hbuf, Wt3, (ushort*)tbuf, n, p1, g2, be2);
  k_agg<<<n / 4, 256, 0, stream>>>(tbuf, row_ptr, csr, dis, hbuf, p2, n);
  k_fc_mx<<<ggrid, 256, 0, stream>>>(hbuf, p2, g3, be3, fWt, fcb, out, n);
}